// Round 11
// baseline (1330.664 us; speedup 1.0000x reference)
//
#include <hip/hip_runtime.h>

// Equivariant graph attention (Transformer_41480794145180) — fp32 throughout.
//
// Pipeline (all on `stream`):
//   k_zero/k_hist/k_scan/k_fill : build CSR of edges grouped by dst node
//   k_dhist/k_dscan/k_dfill     : counting-sort nodes by degree (descending)
//   k_gather: permute xattr/eattr/cutoff/esrc into CSR slot order
//   k_nodeA : per-node A fragments (lane-contiguous layout)
//   k_mlp   : LANE-per-edge dense MLP (8->64->128) -> wm[slot][128].
//             h[64] entirely in registers; weights read via wave-uniform
//             (scalar-path) loads; ZERO LDS. Identical summation order to
//             the previous version (l = 0..63) -> bit-identical results.
//   k_att   : wave-per-node (degree-sorted): logits from wm -> folded reduce
//             -> expw -> z (regs) -> sa (CSR order)
//   k_mlp   : again with V weights, overwriting wm (buffer reuse)
//   k_agg   : wave-per-node: v-terms from wm * sa -> wave agg -> fused
//             output linear -> out
//
// R11 (R10 post-mortem: k_mlp LDS-BW-bound — 96 ds_read_b128/iter/wave
// (32 wq + 64 Hs) shared across 8 waves/CU saturates the LDS unit; swizzle
// fixed conflicts but not volume):
//  - lane-per-edge MLP: hidden vector in VGPRs (no Hs), weight indices
//    wave-uniform -> scalar/SMEM path (no LDS at all). xc loads coalesced
//    (lane == slot). Output written as the same (out[p], out[p+64]) float2
//    pair layout, 64B/lane per chunk.
//  - grid 640, grid-stride, all-resident at 4 waves/SIMD (LDS=0).

constexpr float INV3    = 0.57735026918962576f;  // 1/sqrt(3)
constexpr float INV_SQ8 = 0.35355339059327373f;  // 1/sqrt(N_BASIS=8)
constexpr float INV_HID = 0.125f;                // 1/sqrt(HID=64)
constexpr float INV_FAN = 0.015625f;             // 1/sqrt(4*32*32)
constexpr float INV_L   = 0.125f;                // 1/sqrt(2*MUL=64)
constexpr int   MAXD    = 128;                   // max in-degree (Poisson(32))

// jax.nn.gelu default (approximate=True, tanh form)
__device__ __forceinline__ float gelu_tanh(float x) {
  float u = 0.7978845608028654f * (x + 0.044715f * x * x * x);
  float e = __expf(2.0f * u);            // e=inf / e=0 limits are exact
  return x * (1.0f - 1.0f / (e + 1.0f)); // = 0.5x(1+tanh(u))
}

// ---------------- CSR build ----------------
__global__ void k_zero(int* __restrict__ p, int n) {
  int i = blockIdx.x * 256 + threadIdx.x;
  if (i < n) p[i] = 0;
}

__global__ void k_hist(const int* __restrict__ dst, int* __restrict__ cnt, int E) {
  int e = blockIdx.x * 256 + threadIdx.x;
  if (e < E) atomicAdd(&cnt[dst[e]], 1);
}

// single-block exclusive scan over N counts -> rowptr[0..N]
__global__ __launch_bounds__(256) void k_scan(const int* __restrict__ cnt,
                                              int* __restrict__ rowptr, int N) {
  __shared__ int wsum[4];
  __shared__ int woff[4];
  __shared__ int carry;
  int t = threadIdx.x, wave = t >> 6, lane = t & 63;
  if (t == 0) { carry = 0; rowptr[0] = 0; }
  __syncthreads();
  for (int base = 0; base < N; base += 256) {
    int i = base + t;
    int inc = (i < N) ? cnt[i] : 0;
#pragma unroll
    for (int off = 1; off < 64; off <<= 1) {
      int y = __shfl_up(inc, off, 64);
      if (lane >= off) inc += y;
    }
    if (lane == 63) wsum[wave] = inc;
    __syncthreads();
    if (t == 0) {
      int r = 0;
      for (int w = 0; w < 4; w++) { woff[w] = r; r += wsum[w]; }
    }
    __syncthreads();
    int incl = inc + woff[wave] + carry;
    if (i < N) rowptr[i + 1] = incl;
    __syncthreads();
    if (t == 255) carry = incl;  // padded lanes add 0, so this is the chunk total
    __syncthreads();
  }
}

__global__ void k_fill(const int* __restrict__ dst, const int* __restrict__ rowptr,
                       int* __restrict__ cursor, int* __restrict__ csr, int E) {
  int e = blockIdx.x * 256 + threadIdx.x;
  if (e < E) {
    int d = dst[e];
    int s = atomicAdd(&cursor[d], 1);
    csr[rowptr[d] + s] = e;
  }
}

// ---------------- degree counting sort (descending) ----------------
__global__ void k_dhist(const int* __restrict__ rowptr, int* __restrict__ dbin, int N) {
  int n = blockIdx.x * 256 + threadIdx.x;
  if (n < N) {
    int deg = rowptr[n + 1] - rowptr[n];
    atomicAdd(&dbin[min(deg, 127)], 1);
  }
}

__global__ void k_dscan(const int* __restrict__ dbin, int* __restrict__ doff) {
  if (threadIdx.x == 0 && blockIdx.x == 0) {
    int r = 0;
    for (int d = 127; d >= 0; --d) { doff[d] = r; r += dbin[d]; }
  }
}

__global__ void k_dfill(const int* __restrict__ rowptr, const int* __restrict__ doff,
                        int* __restrict__ dcur, int* __restrict__ nperm, int N) {
  int n = blockIdx.x * 256 + threadIdx.x;
  if (n < N) {
    int d = min(rowptr[n + 1] - rowptr[n], 127);
    int p = doff[d] + atomicAdd(&dcur[d], 1);
    nperm[p] = n;
  }
}

// permute edge arrays into CSR slot order (coalesced writes, random reads)
__global__ __launch_bounds__(256) void k_gather(
    const int* __restrict__ csr, const int* __restrict__ esrc,
    const float* __restrict__ xattr, const float* __restrict__ eattr,
    const float* __restrict__ cutoff,
    float* __restrict__ xc, float* __restrict__ ec, float* __restrict__ cc,
    int* __restrict__ srcc, int E) {
  int p = blockIdx.x * 256 + threadIdx.x;
  if (p >= E) return;
  int e = csr[p];
  srcc[p] = esrc[e];
  cc[p] = cutoff[e];
  ((float4*)ec)[p] = ((const float4*)eattr)[e];
  const float4* xs = (const float4*)xattr + (size_t)e * 2;
  float4* xd = (float4*)xc + (size_t)p * 2;
  xd[0] = xs[0]; xd[1] = xs[1];
}

// ---------------- per-node A precompute ----------------
// A layout per node (1024 f32), lane-contiguous:
//   A0[32][4] (v,h) | A1[32][4] | A2[32][4][3] (v,h,d) | A3[32][4][3]
__global__ __launch_bounds__(256) void k_nodeA(const float* __restrict__ node_f,
                                               const float* __restrict__ Wdot,
                                               float* __restrict__ A, int N) {
  __shared__ float Wd[16384];     // 64 KiB: W_dot[4][4][32][32]
  __shared__ float nfs[32 * 128]; // 16 KiB: 32 nodes' features
  int t = threadIdx.x;
  for (int i = t; i < 16384; i += 256) Wd[i] = Wdot[i];
  int n0 = blockIdx.x * 32;
  int nEnd = min(32, N - n0);
  for (int i = t; i < nEnd * 128; i += 256) nfs[i] = node_f[n0 * 128 + i];
  __syncthreads();
  for (int nn = 0; nn < nEnd; ++nn) {
    const float* nf = &nfs[nn * 128];
    float* An = &A[(n0 + nn) * 1024];
#pragma unroll
    for (int k = 0; k < 4; k++) {
      int o = t + k * 256;  // branch below is uniform per k (no divergence)
      float acc = 0.f;
      int idx;
      if (o < 256) {        // A0 / A1 : scalar q
        int term = o >> 7, h = (o >> 5) & 3, v = o & 31;
        const float* W = &Wd[term * 4096 + h * 1024 + v];
#pragma unroll
        for (int u = 0; u < 32; u++) acc += W[u * 32] * nf[u];
        idx = term * 128 + v * 4 + h;
      } else {              // A2 / A3 : vector q
        int r = o - 256;
        int term = r / 384;                 // 0,1 -> A2,A3
        int rr = r % 384;
        int h = rr / 96, q = rr % 96, v = q / 3, d = q - 3 * (q / 3);
        const float* W = &Wd[(term + 2) * 4096 + h * 1024 + v];
#pragma unroll
        for (int u = 0; u < 32; u++) acc += W[u * 32] * nf[32 + u * 3 + d];
        idx = 256 + term * 384 + v * 12 + h * 3 + d;
      }
      An[idx] = acc;
    }
  }
}

// ---------------- edge-parallel MLP precompute (lane-per-edge, no LDS) --------
// wm[slot][128] as float2 pairs: pair p = (out[p], out[p+64]) * INV_HID,
// p = 0..63 — identical to previous layout/consumer.
__global__ __launch_bounds__(256) void k_mlp(
    const float* __restrict__ xc,      // E x 8, CSR slot order
    const float* __restrict__ w1,      // 8 x 64
    const float* __restrict__ b1,      // 64
    const float* __restrict__ w2,      // 64 x 128
    float* __restrict__ wm,            // E x 128, CSR slot order
    int E)
{
  int lane = threadIdx.x & 63;
  int wave = threadIdx.x >> 6;
  int stride = gridDim.x * 256;

  for (int eb = blockIdx.x * 256 + wave * 64; eb < E; eb += stride) {
    int slot = min(eb + lane, E - 1);
    bool valid = (eb + lane) < E;
    // coalesced input: lane == slot (consecutive)
    const float4* xp = (const float4*)xc + (size_t)slot * 2;
    float4 xa = xp[0], xb = xp[1];
    // layer 1: full hidden vector in registers (indices all compile-time)
    float h[64];
#pragma unroll
    for (int l = 0; l < 64; ++l) {
      float acc = xa.x * w1[l]       + xa.y * w1[64 + l]
                + xa.z * w1[128 + l] + xa.w * w1[192 + l]
                + xb.x * w1[256 + l] + xb.y * w1[320 + l]
                + xb.z * w1[384 + l] + xb.w * w1[448 + l];
      h[l] = gelu_tanh(acc * INV_SQ8 + b1[l]);
    }
    // layer 2: 8 chunks of 8 pairs; inner l fully unrolled (h stays in regs)
    float2* wrow = (float2*)wm + (size_t)slot * 64;
    for (int jc = 0; jc < 8; ++jc) {
      float a0[8] = {0, 0, 0, 0, 0, 0, 0, 0};
      float a1[8] = {0, 0, 0, 0, 0, 0, 0, 0};
      const float* wj = w2 + jc * 8;
#pragma unroll
      for (int l = 0; l < 64; ++l) {
        const float* wr = wj + l * 128;   // wave-uniform address -> scalar path
#pragma unroll
        for (int j = 0; j < 8; ++j) {
          a0[j] += h[l] * wr[j];
          a1[j] += h[l] * wr[64 + j];
        }
      }
      if (valid) {
        float4* wp = (float4*)(wrow + jc * 8);
#pragma unroll
        for (int j = 0; j < 4; ++j) {
          wp[j] = make_float4(a0[2 * j] * INV_HID,     a1[2 * j] * INV_HID,
                              a0[2 * j + 1] * INV_HID, a1[2 * j + 1] * INV_HID);
        }
      }
    }
  }
}

// ---------------- attention pass (wave-per-node, degree-sorted) ----------------
__global__ __launch_bounds__(256) void k_att(
    const int* __restrict__ rowptr,
    const int* __restrict__ nperm,     // degree-sorted node ids
    const int* __restrict__ srcc,      // E, CSR order
    const float* __restrict__ ec,      // E x 4, CSR order
    const float* __restrict__ cc,      // E, CSR order
    const float* __restrict__ node_f,  // N x 128
    const float* __restrict__ wm,      // E x 128 (K-MLP, INV_HID folded)
    const float* __restrict__ A,       // N x 1024 (lane-contiguous layout)
    float* __restrict__ sa_out,        // E x 4, CSR slot order
    int N)
{
  __shared__ float expws[4][MAXD][4];  // per-wave

  int t = threadIdx.x;
  int wave = t >> 6, lane = t & 63;
  int idx = blockIdx.x * 4 + wave;
  if (idx >= N) return;
  int n = nperm[idx];
  int row0 = rowptr[n];
  int deg = min(rowptr[n + 1] - row0, MAXD);
  if (deg <= 0) return;

  int v = lane & 31;
  bool hi = lane >= 32;
  int kk = (lane >> 2) & 3;

  // A fragments in registers
  float aS[4], aV[12];
  {
    const float* Ab = A + (size_t)n * 1024;
    const float* ps = Ab + (hi ? 128 : 0) + v * 4;
    float4 t0 = *(const float4*)ps;
    aS[0] = t0.x; aS[1] = t0.y; aS[2] = t0.z; aS[3] = t0.w;
    const float* pv = Ab + (hi ? 640 : 256) + v * 12;
    float4 u0 = *(const float4*)pv;
    float4 u1 = *(const float4*)(pv + 4);
    float4 u2 = *(const float4*)(pv + 8);
    aV[0] = u0.x; aV[1] = u0.y; aV[2]  = u0.z; aV[3]  = u0.w;
    aV[4] = u1.x; aV[5] = u1.y; aV[6]  = u1.z; aV[7]  = u1.w;
    aV[8] = u2.x; aV[9] = u2.y; aV[10] = u2.z; aV[11] = u2.w;
  }

  int iters = (deg + 3) >> 2;
  float zacc = 0.f;  // lanes 0..15: partial z for (kk, h2=lane&3)

  for (int it = 0; it < iters; ++it) {
    int sb = it * 4;
    int slot[4]; int sp[4];
#pragma unroll
    for (int k = 0; k < 4; k++) slot[k] = row0 + min(sb + k, deg - 1);
#pragma unroll
    for (int k = 0; k < 4; k++) sp[k] = srcc[slot[k]];
    float4 ya[4]; float cf[4]; float2 wj[4]; float s0[4], s1[4], s2[4];
#pragma unroll
    for (int k = 0; k < 4; k++) {
      ya[k] = ((const float4*)ec)[slot[k]];
      cf[k] = (sb + k < deg) ? cc[slot[k]] : 0.f;   // OOB -> expw 0
      wj[k] = ((const float2*)wm)[(size_t)slot[k] * 64 + (hi ? 32 : 0) + v];
      const float* nf = &node_f[(size_t)sp[k] * 128];
      if (!hi) { s0[k] = nf[v]; s1[k] = 0.f; s2[k] = 0.f; }
      else     { s0[k] = nf[32 + v * 3]; s1[k] = nf[33 + v * 3]; s2[k] = nf[34 + v * 3]; }
    }
    // attention logits; p[m], m = k*4 + h2
    float p[16];
#pragma unroll
    for (int k = 0; k < 4; k++) {
      float ys = ya[k].x, yv0 = ya[k].y, yv1 = ya[k].z, yv2 = ya[k].w;
      if (!hi) {  // lanes 0..31: k0 (row 0) + kv0 (row 2)
        float k0 = wj[k].x * s0[k] * ys;
        float kb = INV3 * wj[k].y * s0[k];
#pragma unroll
        for (int h2 = 0; h2 < 4; h2++)
          p[k * 4 + h2] = aS[h2] * k0 +
              kb * (aV[h2 * 3] * yv0 + aV[h2 * 3 + 1] * yv1 + aV[h2 * 3 + 2] * yv2);
      } else {    // lanes 32..63: k1 (row 1) + kv1 (row 3)
        float dotv = s0[k] * yv0 + s1[k] * yv1 + s2[k] * yv2;
        float k1 = wj[k].x * dotv * INV3;
        float kc = INV3 * wj[k].y * ys;
#pragma unroll
        for (int h2 = 0; h2 < 4; h2++)
          p[k * 4 + h2] = aS[h2] * k1 +
              kc * (aV[h2 * 3] * s0[k] + aV[h2 * 3 + 1] * s1[k] + aV[h2 * 3 + 2] * s2[k]);
      }
    }
    // folded butterfly: 16 per-lane values -> full sums keyed by lane&15
    bool fb0 = (lane & 1) != 0;
    float q8[8];
#pragma unroll
    for (int j = 0; j < 8; j++) {
      float a = p[2 * j], b = p[2 * j + 1];
      float keep = fb0 ? b : a, send = fb0 ? a : b;
      q8[j] = keep + __shfl_xor(send, 1, 64);
    }
    bool fb1 = (lane & 2) != 0;
    float r4[4];
#pragma unroll
    for (int j = 0; j < 4; j++) {
      float a = q8[2 * j], b = q8[2 * j + 1];
      float keep = fb1 ? b : a, send = fb1 ? a : b;
      r4[j] = keep + __shfl_xor(send, 2, 64);
    }
    bool fb2 = (lane & 4) != 0;
    float s2v[2];
#pragma unroll
    for (int j = 0; j < 2; j++) {
      float a = r4[2 * j], b = r4[2 * j + 1];
      float keep = fb2 ? b : a, send = fb2 ? a : b;
      s2v[j] = keep + __shfl_xor(send, 4, 64);
    }
    bool fb3 = (lane & 8) != 0;
    float w;
    {
      float a = s2v[0], b = s2v[1];
      float keep = fb3 ? b : a, send = fb3 ? a : b;
      w = keep + __shfl_xor(send, 8, 64);
    }
    w += __shfl_xor(w, 16, 64);
    w += __shfl_xor(w, 32, 64);
    // lane l holds sum for edge (l>>2)&3, head l&3
    float cA = (lane & 4) ? cf[1] : cf[0];
    float cB = (lane & 4) ? cf[3] : cf[2];
    float cfs = (lane & 8) ? cB : cA;
    int slotw = sb + kk;
    float ex = cfs * __expf(w * INV_FAN);
    if (lane < 16 && slotw < deg) {
      expws[wave][slotw][lane & 3] = ex;
      zacc += ex;
    }
  }
  // z reduce: lanes 0..15 hold partials (kk, h2=lane&3); sum over kk
  float zr = zacc;
  zr += __shfl_xor(zr, 4, 64);
  zr += __shfl_xor(zr, 8, 64);
  float zf = __shfl(zr, lane & 3, 64);
  zf = (zf == 0.f) ? 1.f : zf;
  for (int i = lane; i < deg * 4; i += 64) {
    int slot = i >> 2;  // i&3 == lane&3
    float alpha = expws[wave][slot][lane & 3] / zf;
    sa_out[(size_t)(row0 + slot) * 4 + (lane & 3)] = sqrtf(fmaxf(alpha, 0.f));
  }
}

// ---------------- aggregation pass + output linear ----------------
__global__ __launch_bounds__(256) void k_agg(
    const int* __restrict__ rowptr,
    const int* __restrict__ nperm,
    const int* __restrict__ srcc,
    const float* __restrict__ ec,
    const float* __restrict__ node_f,
    const float* __restrict__ wm,      // E x 128 (V-MLP, INV_HID folded)
    const float* __restrict__ Wls, const float* __restrict__ Wlv,  // 64x32 each
    const float* __restrict__ sa_in,   // E x 4, CSR slot order
    float* __restrict__ out,           // N x 128
    int N)
{
  __shared__ float aggv[4][256];  // [wave][ch']: ch'=u (s) | 64+d*64+u (v)

  int t = threadIdx.x;
  int wave = t >> 6, lane = t & 63;
  int idx = blockIdx.x * 4 + wave;
  if (idx >= N) return;
  int n = nperm[idx];
  int row0 = rowptr[n];
  int deg = min(rowptr[n + 1] - row0, MAXD);

  int v = lane & 31;
  bool hi = lane >= 32;
  int hh = v >> 3;  // head of channel v (m = MUL/H = 8)
  float accS = 0.f, acc0 = 0.f, acc1 = 0.f, acc2 = 0.f;

  if (deg > 0) {
    int iters = (deg + 3) >> 2;
    for (int it = 0; it < iters; ++it) {
      int sb = it * 4;
      int slot[4]; int sp[4];
#pragma unroll
      for (int k = 0; k < 4; k++) slot[k] = row0 + min(sb + k, deg - 1);
#pragma unroll
      for (int k = 0; k < 4; k++) sp[k] = srcc[slot[k]];
      float4 ya[4]; float sav[4]; float2 wj[4]; float s0[4], s1[4], s2[4];
#pragma unroll
      for (int k = 0; k < 4; k++) {
        sav[k] = (sb + k < deg) ? sa_in[(size_t)slot[k] * 4 + hh] : 0.f;  // OOB -> 0
        ya[k] = ((const float4*)ec)[slot[k]];
        wj[k] = ((const float2*)wm)[(size_t)slot[k] * 64 + (hi ? 32 : 0) + v];
        const float* nf = &node_f[(size_t)sp[k] * 128];
        if (!hi) { s0[k] = nf[v]; s1[k] = 0.f; s2[k] = 0.f; }
        else     { s0[k] = nf[32 + v * 3]; s1[k] = nf[33 + v * 3]; s2[k] = nf[34 + v * 3]; }
      }
#pragma unroll
      for (int k = 0; k < 4; k++) {
        float ys = ya[k].x, yv0 = ya[k].y, yv1 = ya[k].z, yv2 = ya[k].w;
        float sav_k = sav[k];
        if (!hi) {  // v0 -> s-ch v ; vv0 -> v-ch (u=v, d)
          accS += wj[k].x * s0[k] * ys * sav_k;
          float b = wj[k].y * s0[k] * sav_k;
          acc0 += b * yv0; acc1 += b * yv1; acc2 += b * yv2;
        } else {    // v1 -> s-ch 32+v ; vv1 -> v-ch (u=32+v, d)
          float dotv = s0[k] * yv0 + s1[k] * yv1 + s2[k] * yv2;
          accS += wj[k].x * dotv * INV3 * sav_k;
          float c = wj[k].y * ys * sav_k;
          acc0 += c * s0[k]; acc1 += c * s1[k]; acc2 += c * s2[k];
        }
      }
    }
  }
  // wave-private aggregation + fused output linear (weights from L2)
  {
    int us = hi ? 32 + v : v;
    aggv[wave][us]       = accS;
    aggv[wave][64 + us]  = acc0;
    aggv[wave][128 + us] = acc1;
    aggv[wave][192 + us] = acc2;
    const float* agg = aggv[wave];   // in-wave DS ordering: writes precede reads
#pragma unroll
    for (int rep = 0; rep < 2; ++rep) {
      int o = lane + rep * 64;
      float acc = 0.f;
      if (o < 32) {
#pragma unroll
        for (int u = 0; u < 64; u++) acc += agg[u] * Wls[u * 32 + o];
      } else {
        int i = o - 32, w2 = i / 3, d = i - 3 * w2;
        const float* av = &agg[64 + d * 64];
#pragma unroll
        for (int u = 0; u < 64; u++) acc += av[u] * Wlv[u * 32 + w2];
      }
      out[(size_t)n * 128 + o] = acc * INV_L;
    }
  }
}

// ---------------- host launcher ----------------
extern "C" void kernel_launch(void* const* d_in, const int* in_sizes, int n_in,
                              void* d_out, int out_size, void* d_ws, size_t ws_size,
                              hipStream_t stream) {
  const int*   esrc   = (const int*)d_in[0];
  const int*   edst   = (const int*)d_in[1];
  const float* xattr  = (const float*)d_in[2];
  const float* eattr  = (const float*)d_in[3];
  const float* cutoff = (const float*)d_in[4];
  const float* node_f = (const float*)d_in[5];
  const float* wk1    = (const float*)d_in[6];
  const float* bk1    = (const float*)d_in[7];
  const float* wk2    = (const float*)d_in[8];
  const float* wv1    = (const float*)d_in[9];
  const float* bv1    = (const float*)d_in[10];
  const float* wv2    = (const float*)d_in[11];
  const float* Wdot   = (const float*)d_in[12];
  const float* Wls    = (const float*)d_in[13];
  const float* Wlv    = (const float*)d_in[14];
  float* out = (float*)d_out;

  int E = in_sizes[0];
  int N = in_sizes[5] / 128;

  // workspace layout (~230 MB; wm reused for K-MLP then V-MLP):
  float* A    = (float*)d_ws;                 // N*1024 f32
  float* sa   = A + (size_t)N * 1024;         // E*4 f32
  float* xc   = sa + (size_t)E * 4;           // E*8 f32 (CSR-ordered xattr)
  float* ec   = xc + (size_t)E * 8;           // E*4 f32 (CSR-ordered eattr)
  float* cc   = ec + (size_t)E * 4;           // E f32   (CSR-ordered cutoff)
  int* srcc   = (int*)(cc + (size_t)E);       // E       (CSR-ordered esrc)
  int* counts = srcc + E;                     // N   (zeroed)
  int* cursor = counts + N;                   // N   (zeroed)
  int* dbin   = cursor + N;                   // 128 (zeroed)
  int* dcur   = dbin + 128;                   // 128 (zeroed)
  int* rowptr = dcur + 128;                   // N+1
  int* doff   = rowptr + (N + 1);             // 128
  int* nperm  = doff + 128;                   // N
  int* csr    = nperm + N;                    // E
  float* wm   = (float*)(csr + E);            // E*128 f32 (163.8 MB)

  k_zero<<<(2 * N + 256 + 255) / 256, 256, 0, stream>>>(counts, 2 * N + 256);
  k_hist<<<(E + 255) / 256, 256, 0, stream>>>(edst, counts, E);
  k_scan<<<1, 256, 0, stream>>>(counts, rowptr, N);
  k_fill<<<(E + 255) / 256, 256, 0, stream>>>(edst, rowptr, cursor, csr, E);
  k_dhist<<<(N + 255) / 256, 256, 0, stream>>>(rowptr, dbin, N);
  k_dscan<<<1, 64, 0, stream>>>(dbin, doff);
  k_dfill<<<(N + 255) / 256, 256, 0, stream>>>(rowptr, doff, dcur, nperm, N);
  k_gather<<<(E + 255) / 256, 256, 0, stream>>>(csr, esrc, xattr, eattr, cutoff,
                                                xc, ec, cc, srcc, E);
  k_nodeA<<<(N + 31) / 32, 256, 0, stream>>>(node_f, Wdot, A, N);

  int mgrid = 640;                              // grid-stride, all-resident
  int nb = (N + 3) / 4;                         // one node per wave

  k_mlp<<<mgrid, 256, 0, stream>>>(xc, wk1, bk1, wk2, wm, E);
  k_att<<<nb, 256, 0, stream>>>(rowptr, nperm, srcc, ec, cc, node_f, wm, A, sa, N);
  k_mlp<<<mgrid, 256, 0, stream>>>(xc, wv1, bv1, wv2, wm, E);
  k_agg<<<nb, 256, 0, stream>>>(rowptr, nperm, srcc, ec, node_f, wm,
                                Wls, Wlv, sa, out, N);
}

// Round 14
// 1006.445 us; speedup vs baseline: 1.3221x; 1.3221x over previous
//
#include <hip/hip_runtime.h>

// Equivariant graph attention (Transformer_41480794145180) — fp32 throughout.
//
// Pipeline (all on `stream`):
//   k_zero/k_hist/k_scan/k_fill : build CSR of edges grouped by dst node
//   k_dhist/k_dscan/k_dfill     : counting-sort nodes by degree (descending)
//   k_gather: permute xattr/eattr/cutoff/esrc into CSR slot order
//   k_nodeA : per-node A fragments (lane-contiguous layout)
//   k_mlp   : BLOCK-COOPERATIVE dense MLP (8->64->128) -> wm[slot][128].
//             4 waves co-process 16 edges; wave w owns pair-columns
//             [w*16,(w+1)*16); weights read as broadcast b64 from a [p][l]
//             pair layout; h in block-shared Hs. 2 barriers/16 edges.
//   k_att   : wave-per-node (degree-sorted): logits from wm -> folded reduce
//             -> expw -> z (regs) -> sa (CSR order)
//   k_mlp   : again with V weights, overwriting wm (buffer reuse)
//   k_agg   : wave-per-node: v-terms from wm * sa -> wave agg -> fused
//             output linear -> out
//
// R14 (R12/R13 both died with container failures; audit found MISALIGNED
// ds_read_b128: Hs[16][66] rows are 264B -> odd rows only 8B-aligned, and
// float4 LDS reads from them fault. Fixed: Hs rows padded to 68 floats
// (272B, 16B-aligned; resulting 2-way bank aliasing is free). R12's staging
// race fix retained. Theory unchanged):
//  - co-processing: w2 LDS traffic amortized over 16 edges (4x); reads are
//    broadcast b64 (conflict-free [p][l] pair layout); h block-shared.
//    Per-lane state small -> VGPR ~<=128 -> 4 waves/SIMD; LDS ~40KB.
//  - stores: 16 consecutive pairs per 16-lane group = 128B segments.

constexpr float INV3    = 0.57735026918962576f;  // 1/sqrt(3)
constexpr float INV_SQ8 = 0.35355339059327373f;  // 1/sqrt(N_BASIS=8)
constexpr float INV_HID = 0.125f;                // 1/sqrt(HID=64)
constexpr float INV_FAN = 0.015625f;             // 1/sqrt(4*32*32)
constexpr float INV_L   = 0.125f;                // 1/sqrt(2*MUL=64)
constexpr int   MAXD    = 128;                   // max in-degree (Poisson(32))

// jax.nn.gelu default (approximate=True, tanh form)
__device__ __forceinline__ float gelu_tanh(float x) {
  float u = 0.7978845608028654f * (x + 0.044715f * x * x * x);
  float e = __expf(2.0f * u);            // e=inf / e=0 limits are exact
  return x * (1.0f - 1.0f / (e + 1.0f)); // = 0.5x(1+tanh(u))
}

// ---------------- CSR build ----------------
__global__ void k_zero(int* __restrict__ p, int n) {
  int i = blockIdx.x * 256 + threadIdx.x;
  if (i < n) p[i] = 0;
}

__global__ void k_hist(const int* __restrict__ dst, int* __restrict__ cnt, int E) {
  int e = blockIdx.x * 256 + threadIdx.x;
  if (e < E) atomicAdd(&cnt[dst[e]], 1);
}

// single-block exclusive scan over N counts -> rowptr[0..N]
__global__ __launch_bounds__(256) void k_scan(const int* __restrict__ cnt,
                                              int* __restrict__ rowptr, int N) {
  __shared__ int wsum[4];
  __shared__ int woff[4];
  __shared__ int carry;
  int t = threadIdx.x, wave = t >> 6, lane = t & 63;
  if (t == 0) { carry = 0; rowptr[0] = 0; }
  __syncthreads();
  for (int base = 0; base < N; base += 256) {
    int i = base + t;
    int inc = (i < N) ? cnt[i] : 0;
#pragma unroll
    for (int off = 1; off < 64; off <<= 1) {
      int y = __shfl_up(inc, off, 64);
      if (lane >= off) inc += y;
    }
    if (lane == 63) wsum[wave] = inc;
    __syncthreads();
    if (t == 0) {
      int r = 0;
      for (int w = 0; w < 4; w++) { woff[w] = r; r += wsum[w]; }
    }
    __syncthreads();
    int incl = inc + woff[wave] + carry;
    if (i < N) rowptr[i + 1] = incl;
    __syncthreads();
    if (t == 255) carry = incl;  // padded lanes add 0, so this is the chunk total
    __syncthreads();
  }
}

__global__ void k_fill(const int* __restrict__ dst, const int* __restrict__ rowptr,
                       int* __restrict__ cursor, int* __restrict__ csr, int E) {
  int e = blockIdx.x * 256 + threadIdx.x;
  if (e < E) {
    int d = dst[e];
    int s = atomicAdd(&cursor[d], 1);
    csr[rowptr[d] + s] = e;
  }
}

// ---------------- degree counting sort (descending) ----------------
__global__ void k_dhist(const int* __restrict__ rowptr, int* __restrict__ dbin, int N) {
  int n = blockIdx.x * 256 + threadIdx.x;
  if (n < N) {
    int deg = rowptr[n + 1] - rowptr[n];
    atomicAdd(&dbin[min(deg, 127)], 1);
  }
}

__global__ void k_dscan(const int* __restrict__ dbin, int* __restrict__ doff) {
  if (threadIdx.x == 0 && blockIdx.x == 0) {
    int r = 0;
    for (int d = 127; d >= 0; --d) { doff[d] = r; r += dbin[d]; }
  }
}

__global__ void k_dfill(const int* __restrict__ rowptr, const int* __restrict__ doff,
                        int* __restrict__ dcur, int* __restrict__ nperm, int N) {
  int n = blockIdx.x * 256 + threadIdx.x;
  if (n < N) {
    int d = min(rowptr[n + 1] - rowptr[n], 127);
    int p = doff[d] + atomicAdd(&dcur[d], 1);
    nperm[p] = n;
  }
}

// permute edge arrays into CSR slot order (coalesced writes, random reads)
__global__ __launch_bounds__(256) void k_gather(
    const int* __restrict__ csr, const int* __restrict__ esrc,
    const float* __restrict__ xattr, const float* __restrict__ eattr,
    const float* __restrict__ cutoff,
    float* __restrict__ xc, float* __restrict__ ec, float* __restrict__ cc,
    int* __restrict__ srcc, int E) {
  int p = blockIdx.x * 256 + threadIdx.x;
  if (p >= E) return;
  int e = csr[p];
  srcc[p] = esrc[e];
  cc[p] = cutoff[e];
  ((float4*)ec)[p] = ((const float4*)eattr)[e];
  const float4* xs = (const float4*)xattr + (size_t)e * 2;
  float4* xd = (float4*)xc + (size_t)p * 2;
  xd[0] = xs[0]; xd[1] = xs[1];
}

// ---------------- per-node A precompute ----------------
// A layout per node (1024 f32), lane-contiguous:
//   A0[32][4] (v,h) | A1[32][4] | A2[32][4][3] (v,h,d) | A3[32][4][3]
__global__ __launch_bounds__(256) void k_nodeA(const float* __restrict__ node_f,
                                               const float* __restrict__ Wdot,
                                               float* __restrict__ A, int N) {
  __shared__ float Wd[16384];     // 64 KiB: W_dot[4][4][32][32]
  __shared__ float nfs[32 * 128]; // 16 KiB: 32 nodes' features
  int t = threadIdx.x;
  for (int i = t; i < 16384; i += 256) Wd[i] = Wdot[i];
  int n0 = blockIdx.x * 32;
  int nEnd = min(32, N - n0);
  for (int i = t; i < nEnd * 128; i += 256) nfs[i] = node_f[n0 * 128 + i];
  __syncthreads();
  for (int nn = 0; nn < nEnd; ++nn) {
    const float* nf = &nfs[nn * 128];
    float* An = &A[(n0 + nn) * 1024];
#pragma unroll
    for (int k = 0; k < 4; k++) {
      int o = t + k * 256;  // branch below is uniform per k (no divergence)
      float acc = 0.f;
      int idx;
      if (o < 256) {        // A0 / A1 : scalar q
        int term = o >> 7, h = (o >> 5) & 3, v = o & 31;
        const float* W = &Wd[term * 4096 + h * 1024 + v];
#pragma unroll
        for (int u = 0; u < 32; u++) acc += W[u * 32] * nf[u];
        idx = term * 128 + v * 4 + h;
      } else {              // A2 / A3 : vector q
        int r = o - 256;
        int term = r / 384;                 // 0,1 -> A2,A3
        int rr = r % 384;
        int h = rr / 96, q = rr % 96, v = q / 3, d = q - 3 * (q / 3);
        const float* W = &Wd[(term + 2) * 4096 + h * 1024 + v];
#pragma unroll
        for (int u = 0; u < 32; u++) acc += W[u * 32] * nf[32 + u * 3 + d];
        idx = 256 + term * 384 + v * 12 + h * 3 + d;
      }
      An[idx] = acc;
    }
  }
}

// ---------------- block-cooperative MLP precompute ----------------
// wm[slot][128] as float2 pairs: pair p = (out[p], out[p+64]) * INV_HID.
// Block processes 16 edges per iteration:
//   layer 1: wave w computes h[e = w+4s][l = lane], s=0..3 -> Hs (shared)
//   layer 2: wave w owns pairs p in [w*16,(w+1)*16); lane = (e-group, p);
//            weights from wqs[p][l] (pair layout, row-padded).
__global__ __launch_bounds__(256) void k_mlp(
    const float* __restrict__ xc,      // E x 8, CSR slot order
    const float* __restrict__ w1,      // 8 x 64
    const float* __restrict__ b1,      // 64
    const float* __restrict__ w2,      // 64 x 128
    float* __restrict__ wm,            // E x 128, CSR slot order
    int E, int chunk)
{
  __shared__ __align__(16) float w1s[512];
  __shared__ float b1s[64];
  __shared__ __align__(16) float2 wqs[64][65];  // [p][l] pairs, row-padded (520B rows, b64-aligned)
  __shared__ __align__(16) float Hs[16][68];    // [edge][l]; 272B rows keep float4 reads 16B-aligned

  int t = threadIdx.x;
  int wave = t >> 6, lane = t & 63;
  for (int i = t; i < 512; i += 256) w1s[i] = w1[i];
  if (t < 64) b1s[t] = b1[t];
  for (int i = t; i < 4096; i += 256) {
    int l = i >> 6, p = i & 63;
    wqs[p][l] = make_float2(w2[l * 128 + p], w2[l * 128 + 64 + p]);
  }
  __syncthreads();  // staging complete before any wave reads w1s/b1s/wqs

  int base = blockIdx.x * chunk;
  int end = min(base + chunk, E);
  int p    = (wave << 4) + (lane & 15);  // this lane's pair column
  int esub = lane >> 4;                  // edge group 0..3 (edges esub*4+s)

  for (int sb = base; sb < end; sb += 16) {
    // ---- layer 1: wave w -> h[e = w+4s][lane] ----
    float hv[4];
#pragma unroll
    for (int s = 0; s < 4; ++s) {
      int slot = min(sb + wave + 4 * s, E - 1);
      const float4* xp = (const float4*)xc + (size_t)slot * 2;
      float4 xa = xp[0], xb = xp[1];
      float acc = xa.x * w1s[lane]       + xa.y * w1s[64 + lane]
                + xa.z * w1s[128 + lane] + xa.w * w1s[192 + lane]
                + xb.x * w1s[256 + lane] + xb.y * w1s[320 + lane]
                + xb.z * w1s[384 + lane] + xb.w * w1s[448 + lane];
      hv[s] = gelu_tanh(acc * INV_SQ8 + b1s[lane]);
    }
    __syncthreads();  // WAR: previous iteration's Hs readers are done
#pragma unroll
    for (int s = 0; s < 4; ++s) Hs[wave + 4 * s][lane] = hv[s];
    __syncthreads();  // RAW: Hs ready
    // ---- layer 2: lane covers pair p for edges esub*4+s ----
    float a0[4] = {0, 0, 0, 0}, a1[4] = {0, 0, 0, 0};
    for (int lb = 0; lb < 16; ++lb) {
      float2 wl0 = wqs[p][lb * 4 + 0];
      float2 wl1 = wqs[p][lb * 4 + 1];
      float2 wl2 = wqs[p][lb * 4 + 2];
      float2 wl3 = wqs[p][lb * 4 + 3];
#pragma unroll
      for (int s = 0; s < 4; ++s) {
        int e = esub * 4 + s;
        float4 hq = *(const float4*)&Hs[e][lb * 4];  // 16B-aligned broadcast
        a0[s] += hq.x * wl0.x + hq.y * wl1.x + hq.z * wl2.x + hq.w * wl3.x;
        a1[s] += hq.x * wl0.y + hq.y * wl1.y + hq.z * wl2.y + hq.w * wl3.y;
      }
    }
    // ---- store: 16-lane group writes 16 consecutive pairs (128B segment) ----
#pragma unroll
    for (int s = 0; s < 4; ++s) {
      int slot = sb + esub * 4 + s;
      if (slot < end) {
        ((float2*)wm)[(size_t)slot * 64 + p] =
            make_float2(a0[s] * INV_HID, a1[s] * INV_HID);
      }
    }
  }
}

// ---------------- attention pass (wave-per-node, degree-sorted) ----------------
__global__ __launch_bounds__(256) void k_att(
    const int* __restrict__ rowptr,
    const int* __restrict__ nperm,     // degree-sorted node ids
    const int* __restrict__ srcc,      // E, CSR order
    const float* __restrict__ ec,      // E x 4, CSR order
    const float* __restrict__ cc,      // E, CSR order
    const float* __restrict__ node_f,  // N x 128
    const float* __restrict__ wm,      // E x 128 (K-MLP, INV_HID folded)
    const float* __restrict__ A,       // N x 1024 (lane-contiguous layout)
    float* __restrict__ sa_out,        // E x 4, CSR slot order
    int N)
{
  __shared__ float expws[4][MAXD][4];  // per-wave

  int t = threadIdx.x;
  int wave = t >> 6, lane = t & 63;
  int idx = blockIdx.x * 4 + wave;
  if (idx >= N) return;
  int n = nperm[idx];
  int row0 = rowptr[n];
  int deg = min(rowptr[n + 1] - row0, MAXD);
  if (deg <= 0) return;

  int v = lane & 31;
  bool hi = lane >= 32;
  int kk = (lane >> 2) & 3;

  // A fragments in registers
  float aS[4], aV[12];
  {
    const float* Ab = A + (size_t)n * 1024;
    const float* ps = Ab + (hi ? 128 : 0) + v * 4;
    float4 t0 = *(const float4*)ps;
    aS[0] = t0.x; aS[1] = t0.y; aS[2] = t0.z; aS[3] = t0.w;
    const float* pv = Ab + (hi ? 640 : 256) + v * 12;
    float4 u0 = *(const float4*)pv;
    float4 u1 = *(const float4*)(pv + 4);
    float4 u2 = *(const float4*)(pv + 8);
    aV[0] = u0.x; aV[1] = u0.y; aV[2]  = u0.z; aV[3]  = u0.w;
    aV[4] = u1.x; aV[5] = u1.y; aV[6]  = u1.z; aV[7]  = u1.w;
    aV[8] = u2.x; aV[9] = u2.y; aV[10] = u2.z; aV[11] = u2.w;
  }

  int iters = (deg + 3) >> 2;
  float zacc = 0.f;  // lanes 0..15: partial z for (kk, h2=lane&3)

  for (int it = 0; it < iters; ++it) {
    int sb = it * 4;
    int slot[4]; int sp[4];
#pragma unroll
    for (int k = 0; k < 4; k++) slot[k] = row0 + min(sb + k, deg - 1);
#pragma unroll
    for (int k = 0; k < 4; k++) sp[k] = srcc[slot[k]];
    float4 ya[4]; float cf[4]; float2 wj[4]; float s0[4], s1[4], s2[4];
#pragma unroll
    for (int k = 0; k < 4; k++) {
      ya[k] = ((const float4*)ec)[slot[k]];
      cf[k] = (sb + k < deg) ? cc[slot[k]] : 0.f;   // OOB -> expw 0
      wj[k] = ((const float2*)wm)[(size_t)slot[k] * 64 + (hi ? 32 : 0) + v];
      const float* nf = &node_f[(size_t)sp[k] * 128];
      if (!hi) { s0[k] = nf[v]; s1[k] = 0.f; s2[k] = 0.f; }
      else     { s0[k] = nf[32 + v * 3]; s1[k] = nf[33 + v * 3]; s2[k] = nf[34 + v * 3]; }
    }
    // attention logits; p[m], m = k*4 + h2
    float p4[16];
#pragma unroll
    for (int k = 0; k < 4; k++) {
      float ys = ya[k].x, yv0 = ya[k].y, yv1 = ya[k].z, yv2 = ya[k].w;
      if (!hi) {  // lanes 0..31: k0 (row 0) + kv0 (row 2)
        float k0 = wj[k].x * s0[k] * ys;
        float kb = INV3 * wj[k].y * s0[k];
#pragma unroll
        for (int h2 = 0; h2 < 4; h2++)
          p4[k * 4 + h2] = aS[h2] * k0 +
              kb * (aV[h2 * 3] * yv0 + aV[h2 * 3 + 1] * yv1 + aV[h2 * 3 + 2] * yv2);
      } else {    // lanes 32..63: k1 (row 1) + kv1 (row 3)
        float dotv = s0[k] * yv0 + s1[k] * yv1 + s2[k] * yv2;
        float k1 = wj[k].x * dotv * INV3;
        float kc = INV3 * wj[k].y * ys;
#pragma unroll
        for (int h2 = 0; h2 < 4; h2++)
          p4[k * 4 + h2] = aS[h2] * k1 +
              kc * (aV[h2 * 3] * s0[k] + aV[h2 * 3 + 1] * s1[k] + aV[h2 * 3 + 2] * s2[k]);
      }
    }
    // folded butterfly: 16 per-lane values -> full sums keyed by lane&15
    bool fb0 = (lane & 1) != 0;
    float q8[8];
#pragma unroll
    for (int j = 0; j < 8; j++) {
      float a = p4[2 * j], b = p4[2 * j + 1];
      float keep = fb0 ? b : a, send = fb0 ? a : b;
      q8[j] = keep + __shfl_xor(send, 1, 64);
    }
    bool fb1 = (lane & 2) != 0;
    float r4[4];
#pragma unroll
    for (int j = 0; j < 4; j++) {
      float a = q8[2 * j], b = q8[2 * j + 1];
      float keep = fb1 ? b : a, send = fb1 ? a : b;
      r4[j] = keep + __shfl_xor(send, 2, 64);
    }
    bool fb2 = (lane & 4) != 0;
    float s2v[2];
#pragma unroll
    for (int j = 0; j < 2; j++) {
      float a = r4[2 * j], b = r4[2 * j + 1];
      float keep = fb2 ? b : a, send = fb2 ? a : b;
      s2v[j] = keep + __shfl_xor(send, 4, 64);
    }
    bool fb3 = (lane & 8) != 0;
    float w;
    {
      float a = s2v[0], b = s2v[1];
      float keep = fb3 ? b : a, send = fb3 ? a : b;
      w = keep + __shfl_xor(send, 8, 64);
    }
    w += __shfl_xor(w, 16, 64);
    w += __shfl_xor(w, 32, 64);
    // lane l holds sum for edge (l>>2)&3, head l&3
    float cA = (lane & 4) ? cf[1] : cf[0];
    float cB = (lane & 4) ? cf[3] : cf[2];
    float cfs = (lane & 8) ? cB : cA;
    int slotw = sb + kk;
    float ex = cfs * __expf(w * INV_FAN);
    if (lane < 16 && slotw < deg) {
      expws[wave][slotw][lane & 3] = ex;
      zacc += ex;
    }
  }
  // z reduce: lanes 0..15 hold partials (kk, h2=lane&3); sum over kk
  float zr = zacc;
  zr += __shfl_xor(zr, 4, 64);
  zr += __shfl_xor(zr, 8, 64);
  float zf = __shfl(zr, lane & 3, 64);
  zf = (zf == 0.f) ? 1.f : zf;
  for (int i = lane; i < deg * 4; i += 64) {
    int slot = i >> 2;  // i&3 == lane&3
    float alpha = expws[wave][slot][lane & 3] / zf;
    sa_out[(size_t)(row0 + slot) * 4 + (lane & 3)] = sqrtf(fmaxf(alpha, 0.f));
  }
}

// ---------------- aggregation pass + output linear ----------------
__global__ __launch_bounds__(256) void k_agg(
    const int* __restrict__ rowptr,
    const int* __restrict__ nperm,
    const int* __restrict__ srcc,
    const float* __restrict__ ec,
    const float* __restrict__ node_f,
    const float* __restrict__ wm,      // E x 128 (V-MLP, INV_HID folded)
    const float* __restrict__ Wls, const float* __restrict__ Wlv,  // 64x32 each
    const float* __restrict__ sa_in,   // E x 4, CSR slot order
    float* __restrict__ out,           // N x 128
    int N)
{
  __shared__ float aggv[4][256];  // [wave][ch']: ch'=u (s) | 64+d*64+u (v)

  int t = threadIdx.x;
  int wave = t >> 6, lane = t & 63;
  int idx = blockIdx.x * 4 + wave;
  if (idx >= N) return;
  int n = nperm[idx];
  int row0 = rowptr[n];
  int deg = min(rowptr[n + 1] - row0, MAXD);

  int v = lane & 31;
  bool hi = lane >= 32;
  int hh = v >> 3;  // head of channel v (m = MUL/H = 8)
  float accS = 0.f, acc0 = 0.f, acc1 = 0.f, acc2 = 0.f;

  if (deg > 0) {
    int iters = (deg + 3) >> 2;
    for (int it = 0; it < iters; ++it) {
      int sb = it * 4;
      int slot[4]; int sp[4];
#pragma unroll
      for (int k = 0; k < 4; k++) slot[k] = row0 + min(sb + k, deg - 1);
#pragma unroll
      for (int k = 0; k < 4; k++) sp[k] = srcc[slot[k]];
      float4 ya[4]; float sav[4]; float2 wj[4]; float s0[4], s1[4], s2[4];
#pragma unroll
      for (int k = 0; k < 4; k++) {
        sav[k] = (sb + k < deg) ? sa_in[(size_t)slot[k] * 4 + hh] : 0.f;  // OOB -> 0
        ya[k] = ((const float4*)ec)[slot[k]];
        wj[k] = ((const float2*)wm)[(size_t)slot[k] * 64 + (hi ? 32 : 0) + v];
        const float* nf = &node_f[(size_t)sp[k] * 128];
        if (!hi) { s0[k] = nf[v]; s1[k] = 0.f; s2[k] = 0.f; }
        else     { s0[k] = nf[32 + v * 3]; s1[k] = nf[33 + v * 3]; s2[k] = nf[34 + v * 3]; }
      }
#pragma unroll
      for (int k = 0; k < 4; k++) {
        float ys = ya[k].x, yv0 = ya[k].y, yv1 = ya[k].z, yv2 = ya[k].w;
        float sav_k = sav[k];
        if (!hi) {  // v0 -> s-ch v ; vv0 -> v-ch (u=v, d)
          accS += wj[k].x * s0[k] * ys * sav_k;
          float b = wj[k].y * s0[k] * sav_k;
          acc0 += b * yv0; acc1 += b * yv1; acc2 += b * yv2;
        } else {    // v1 -> s-ch 32+v ; vv1 -> v-ch (u=32+v, d)
          float dotv = s0[k] * yv0 + s1[k] * yv1 + s2[k] * yv2;
          accS += wj[k].x * dotv * INV3 * sav_k;
          float c = wj[k].y * ys * sav_k;
          acc0 += c * s0[k]; acc1 += c * s1[k]; acc2 += c * s2[k];
        }
      }
    }
  }
  // wave-private aggregation + fused output linear (weights from L2)
  {
    int us = hi ? 32 + v : v;
    aggv[wave][us]       = accS;
    aggv[wave][64 + us]  = acc0;
    aggv[wave][128 + us] = acc1;
    aggv[wave][192 + us] = acc2;
    const float* agg = aggv[wave];   // in-wave DS ordering: writes precede reads
#pragma unroll
    for (int rep = 0; rep < 2; ++rep) {
      int o = lane + rep * 64;
      float acc = 0.f;
      if (o < 32) {
#pragma unroll
        for (int u = 0; u < 64; u++) acc += agg[u] * Wls[u * 32 + o];
      } else {
        int i = o - 32, w2 = i / 3, d = i - 3 * w2;
        const float* av = &agg[64 + d * 64];
#pragma unroll
        for (int u = 0; u < 64; u++) acc += av[u] * Wlv[u * 32 + w2];
      }
      out[(size_t)n * 128 + o] = acc * INV_L;
    }
  }
}

// ---------------- host launcher ----------------
extern "C" void kernel_launch(void* const* d_in, const int* in_sizes, int n_in,
                              void* d_out, int out_size, void* d_ws, size_t ws_size,
                              hipStream_t stream) {
  const int*   esrc   = (const int*)d_in[0];
  const int*   edst   = (const int*)d_in[1];
  const float* xattr  = (const float*)d_in[2];
  const float* eattr  = (const float*)d_in[3];
  const float* cutoff = (const float*)d_in[4];
  const float* node_f = (const float*)d_in[5];
  const float* wk1    = (const float*)d_in[6];
  const float* bk1    = (const float*)d_in[7];
  const float* wk2    = (const float*)d_in[8];
  const float* wv1    = (const float*)d_in[9];
  const float* bv1    = (const float*)d_in[10];
  const float* wv2    = (const float*)d_in[11];
  const float* Wdot   = (const float*)d_in[12];
  const float* Wls    = (const float*)d_in[13];
  const float* Wlv    = (const float*)d_in[14];
  float* out = (float*)d_out;

  int E = in_sizes[0];
  int N = in_sizes[5] / 128;

  // workspace layout (~230 MB; wm reused for K-MLP then V-MLP):
  float* A    = (float*)d_ws;                 // N*1024 f32
  float* sa   = A + (size_t)N * 1024;         // E*4 f32
  float* xc   = sa + (size_t)E * 4;           // E*8 f32 (CSR-ordered xattr)
  float* ec   = xc + (size_t)E * 8;           // E*4 f32 (CSR-ordered eattr)
  float* cc   = ec + (size_t)E * 4;           // E f32   (CSR-ordered cutoff)
  int* srcc   = (int*)(cc + (size_t)E);       // E       (CSR-ordered esrc)
  int* counts = srcc + E;                     // N   (zeroed)
  int* cursor = counts + N;                   // N   (zeroed)
  int* dbin   = cursor + N;                   // 128 (zeroed)
  int* dcur   = dbin + 128;                   // 128 (zeroed)
  int* rowptr = dcur + 128;                   // N+1
  int* doff   = rowptr + (N + 1);             // 128
  int* nperm  = doff + 128;                   // N
  int* csr    = nperm + N;                    // E
  float* wm   = (float*)(csr + E);            // E*128 f32 (163.8 MB)

  k_zero<<<(2 * N + 256 + 255) / 256, 256, 0, stream>>>(counts, 2 * N + 256);
  k_hist<<<(E + 255) / 256, 256, 0, stream>>>(edst, counts, E);
  k_scan<<<1, 256, 0, stream>>>(counts, rowptr, N);
  k_fill<<<(E + 255) / 256, 256, 0, stream>>>(edst, rowptr, cursor, csr, E);
  k_dhist<<<(N + 255) / 256, 256, 0, stream>>>(rowptr, dbin, N);
  k_dscan<<<1, 64, 0, stream>>>(dbin, doff);
  k_dfill<<<(N + 255) / 256, 256, 0, stream>>>(rowptr, doff, dcur, nperm, N);
  k_gather<<<(E + 255) / 256, 256, 0, stream>>>(csr, esrc, xattr, eattr, cutoff,
                                                xc, ec, cc, srcc, E);
  k_nodeA<<<(N + 31) / 32, 256, 0, stream>>>(node_f, Wdot, A, N);

  int mgrid = 512;                              // all-resident, no tail
  int chunk = ((E + mgrid - 1) / mgrid + 15) & ~15;  // multiple of 16
  int nb = (N + 3) / 4;                         // one node per wave

  k_mlp<<<mgrid, 256, 0, stream>>>(xc, wk1, bk1, wk2, wm, E, chunk);
  k_att<<<nb, 256, 0, stream>>>(rowptr, nperm, srcc, ec, cc, node_f, wm, A, sa, N);
  k_mlp<<<mgrid, 256, 0, stream>>>(xc, wv1, bv1, wv2, wm, E, chunk);
  k_agg<<<nb, 256, 0, stream>>>(rowptr, nperm, srcc, ec, node_f, wm,
                                Wls, Wlv, sa, out, N);
}

// Round 15
// 881.780 us; speedup vs baseline: 1.5091x; 1.1414x over previous
//
#include <hip/hip_runtime.h>

// Equivariant graph attention (Transformer_41480794145180) — fp32 throughout.
//
// Pipeline (all on `stream`):
//   k_zero/k_hist/k_scan/k_fill : build CSR of edges grouped by dst node
//   k_dhist/k_dscan/k_dfill     : counting-sort nodes by degree (descending)
//   k_gather: permute xattr/eattr/cutoff/esrc into CSR slot order
//   k_nodeA : per-node A fragments (lane-contiguous layout)
//   k_mlp   : edge-parallel dense MLP (8->64->128) -> wm[slot][128];
//             xc read linearly; wq bank-conflict-free via XOR swizzle
//   k_att   : wave-per-node (degree-sorted): logits from wm -> folded reduce
//             -> expw -> z (regs) -> sa (CSR order)
//   k_mlp   : again with V weights, overwriting wm (buffer reuse)
//   k_agg   : wave-per-node: v-terms from wm * sa -> wave agg -> fused
//             output linear -> out
//
// R15 (R14 post-mortem: block-coop MLP LOST to R10 — VGPR 200 not <=128,
// 2 barriers/16edges + Hs round-trip at 2 waves/SIMD -> VALU 34.6%, 316us.
// THIRD failed k_mlp redesign; revert to R10's 4-edge/wave structure):
//  - ONE delta vs R10: k_mlp grid 512 -> 768. VGPR=168 allows 3 waves/SIMD
//    (floor(512/168)=3) = 3 blocks/CU residency; 512 blocks ran the machine
//    at 2/CU (2/3 of its own limit). 768 = exact residency fill, no tail.

constexpr float INV3    = 0.57735026918962576f;  // 1/sqrt(3)
constexpr float INV_SQ8 = 0.35355339059327373f;  // 1/sqrt(N_BASIS=8)
constexpr float INV_HID = 0.125f;                // 1/sqrt(HID=64)
constexpr float INV_FAN = 0.015625f;             // 1/sqrt(4*32*32)
constexpr float INV_L   = 0.125f;                // 1/sqrt(2*MUL=64)
constexpr int   MAXD    = 128;                   // max in-degree (Poisson(32))

// jax.nn.gelu default (approximate=True, tanh form)
__device__ __forceinline__ float gelu_tanh(float x) {
  float u = 0.7978845608028654f * (x + 0.044715f * x * x * x);
  float e = __expf(2.0f * u);            // e=inf / e=0 limits are exact
  return x * (1.0f - 1.0f / (e + 1.0f)); // = 0.5x(1+tanh(u))
}

// ---------------- CSR build ----------------
__global__ void k_zero(int* __restrict__ p, int n) {
  int i = blockIdx.x * 256 + threadIdx.x;
  if (i < n) p[i] = 0;
}

__global__ void k_hist(const int* __restrict__ dst, int* __restrict__ cnt, int E) {
  int e = blockIdx.x * 256 + threadIdx.x;
  if (e < E) atomicAdd(&cnt[dst[e]], 1);
}

// single-block exclusive scan over N counts -> rowptr[0..N]
__global__ __launch_bounds__(256) void k_scan(const int* __restrict__ cnt,
                                              int* __restrict__ rowptr, int N) {
  __shared__ int wsum[4];
  __shared__ int woff[4];
  __shared__ int carry;
  int t = threadIdx.x, wave = t >> 6, lane = t & 63;
  if (t == 0) { carry = 0; rowptr[0] = 0; }
  __syncthreads();
  for (int base = 0; base < N; base += 256) {
    int i = base + t;
    int inc = (i < N) ? cnt[i] : 0;
#pragma unroll
    for (int off = 1; off < 64; off <<= 1) {
      int y = __shfl_up(inc, off, 64);
      if (lane >= off) inc += y;
    }
    if (lane == 63) wsum[wave] = inc;
    __syncthreads();
    if (t == 0) {
      int r = 0;
      for (int w = 0; w < 4; w++) { woff[w] = r; r += wsum[w]; }
    }
    __syncthreads();
    int incl = inc + woff[wave] + carry;
    if (i < N) rowptr[i + 1] = incl;
    __syncthreads();
    if (t == 255) carry = incl;  // padded lanes add 0, so this is the chunk total
    __syncthreads();
  }
}

__global__ void k_fill(const int* __restrict__ dst, const int* __restrict__ rowptr,
                       int* __restrict__ cursor, int* __restrict__ csr, int E) {
  int e = blockIdx.x * 256 + threadIdx.x;
  if (e < E) {
    int d = dst[e];
    int s = atomicAdd(&cursor[d], 1);
    csr[rowptr[d] + s] = e;
  }
}

// ---------------- degree counting sort (descending) ----------------
__global__ void k_dhist(const int* __restrict__ rowptr, int* __restrict__ dbin, int N) {
  int n = blockIdx.x * 256 + threadIdx.x;
  if (n < N) {
    int deg = rowptr[n + 1] - rowptr[n];
    atomicAdd(&dbin[min(deg, 127)], 1);
  }
}

__global__ void k_dscan(const int* __restrict__ dbin, int* __restrict__ doff) {
  if (threadIdx.x == 0 && blockIdx.x == 0) {
    int r = 0;
    for (int d = 127; d >= 0; --d) { doff[d] = r; r += dbin[d]; }
  }
}

__global__ void k_dfill(const int* __restrict__ rowptr, const int* __restrict__ doff,
                        int* __restrict__ dcur, int* __restrict__ nperm, int N) {
  int n = blockIdx.x * 256 + threadIdx.x;
  if (n < N) {
    int d = min(rowptr[n + 1] - rowptr[n], 127);
    int p = doff[d] + atomicAdd(&dcur[d], 1);
    nperm[p] = n;
  }
}

// permute edge arrays into CSR slot order (coalesced writes, random reads)
__global__ __launch_bounds__(256) void k_gather(
    const int* __restrict__ csr, const int* __restrict__ esrc,
    const float* __restrict__ xattr, const float* __restrict__ eattr,
    const float* __restrict__ cutoff,
    float* __restrict__ xc, float* __restrict__ ec, float* __restrict__ cc,
    int* __restrict__ srcc, int E) {
  int p = blockIdx.x * 256 + threadIdx.x;
  if (p >= E) return;
  int e = csr[p];
  srcc[p] = esrc[e];
  cc[p] = cutoff[e];
  ((float4*)ec)[p] = ((const float4*)eattr)[e];
  const float4* xs = (const float4*)xattr + (size_t)e * 2;
  float4* xd = (float4*)xc + (size_t)p * 2;
  xd[0] = xs[0]; xd[1] = xs[1];
}

// ---------------- per-node A precompute ----------------
// A layout per node (1024 f32), lane-contiguous:
//   A0[32][4] (v,h) | A1[32][4] | A2[32][4][3] (v,h,d) | A3[32][4][3]
__global__ __launch_bounds__(256) void k_nodeA(const float* __restrict__ node_f,
                                               const float* __restrict__ Wdot,
                                               float* __restrict__ A, int N) {
  __shared__ float Wd[16384];     // 64 KiB: W_dot[4][4][32][32]
  __shared__ float nfs[32 * 128]; // 16 KiB: 32 nodes' features
  int t = threadIdx.x;
  for (int i = t; i < 16384; i += 256) Wd[i] = Wdot[i];
  int n0 = blockIdx.x * 32;
  int nEnd = min(32, N - n0);
  for (int i = t; i < nEnd * 128; i += 256) nfs[i] = node_f[n0 * 128 + i];
  __syncthreads();
  for (int nn = 0; nn < nEnd; ++nn) {
    const float* nf = &nfs[nn * 128];
    float* An = &A[(n0 + nn) * 1024];
#pragma unroll
    for (int k = 0; k < 4; k++) {
      int o = t + k * 256;  // branch below is uniform per k (no divergence)
      float acc = 0.f;
      int idx;
      if (o < 256) {        // A0 / A1 : scalar q
        int term = o >> 7, h = (o >> 5) & 3, v = o & 31;
        const float* W = &Wd[term * 4096 + h * 1024 + v];
#pragma unroll
        for (int u = 0; u < 32; u++) acc += W[u * 32] * nf[u];
        idx = term * 128 + v * 4 + h;
      } else {              // A2 / A3 : vector q
        int r = o - 256;
        int term = r / 384;                 // 0,1 -> A2,A3
        int rr = r % 384;
        int h = rr / 96, q = rr % 96, v = q / 3, d = q - 3 * (q / 3);
        const float* W = &Wd[(term + 2) * 4096 + h * 1024 + v];
#pragma unroll
        for (int u = 0; u < 32; u++) acc += W[u * 32] * nf[32 + u * 3 + d];
        idx = 256 + term * 384 + v * 12 + h * 3 + d;
      }
      An[idx] = acc;
    }
  }
}

// ---------------- edge-parallel MLP precompute ----------------
// wm[slot][128] layout: [lo half: (row0[v],row2[v]) pairs, v=0..31]
//                       [hi half: (row1[v],row3[v]) pairs, v=0..31]
// Pre-scaled by INV_HID. Input xc read LINEARLY by slot (CSR order).
// wq column index XOR-swizzled (j -> j^((j>>3)&7), float4 granularity) so the
// per-lane 16B-stride weight reads are bank-conflict-free (both write & read).
__global__ __launch_bounds__(256) void k_mlp(
    const float* __restrict__ xc,      // E x 8, CSR slot order
    const float* __restrict__ w1, const float* __restrict__ b1,
    const float* __restrict__ w2,
    float* __restrict__ wm,            // E x 128, CSR slot order
    int E, int chunk)
{
  __shared__ __align__(16) float w1s[512];
  __shared__ float b1s[64];
  __shared__ __align__(16) float wq[16][128][4];  // wq[l/4][j_swz][l%4] = w2[l][j]
  __shared__ __align__(16) float Hs[4][4][64];    // wave-private

  int t = threadIdx.x;
  int wave = t >> 6, lane = t & 63;
  for (int i = t; i < 512; i += 256) w1s[i] = w1[i];
  if (t < 64) b1s[t] = b1[t];
  for (int i = t; i < 8192; i += 256) {
    int l = i >> 7, j = i & 127;
    int js = j ^ ((j >> 3) & 7);                  // swizzled column
    wq[l >> 2][js][l & 3] = w2[i];
  }
  __syncthreads();

  int base = blockIdx.x * chunk;
  int end = min(base + chunk, E);
  int v = lane & 31;
  bool hi = lane >= 32;
  // swizzled read columns for this lane's two outputs (j=lane, j=lane+64)
  int c0 = lane, c1 = lane + 64;
  int c0s = c0 ^ ((c0 >> 3) & 7);
  int c1s = c1 ^ ((c1 >> 3) & 7);

  for (int sb = base + wave * 4; sb < end; sb += 16) {
    int sl[4];
#pragma unroll
    for (int k = 0; k < 4; k++) sl[k] = min(sb + k, E - 1);
    float h[4];
#pragma unroll
    for (int k = 0; k < 4; k++) {
      const float4* xp = (const float4*)xc + (size_t)sl[k] * 2;  // linear stream
      float4 xa = xp[0], xb = xp[1];
      float acc = xa.x * w1s[lane]       + xa.y * w1s[64 + lane]
                + xa.z * w1s[128 + lane] + xa.w * w1s[192 + lane]
                + xb.x * w1s[256 + lane] + xb.y * w1s[320 + lane]
                + xb.z * w1s[384 + lane] + xb.w * w1s[448 + lane];
      h[k] = gelu_tanh(acc * INV_SQ8 + b1s[lane]);
    }
#pragma unroll
    for (int k = 0; k < 4; k++) Hs[wave][k][lane] = h[k];  // wave-private
    float a0[4] = {0, 0, 0, 0}, a1[4] = {0, 0, 0, 0};
#pragma unroll
    for (int q = 0; q < 16; q++) {
      float4 wA = *(const float4*)&wq[q][c0s][0];   // conflict-free (swizzled)
      float4 wB = *(const float4*)&wq[q][c1s][0];
#pragma unroll
      for (int k = 0; k < 4; k++) {
        float4 hq = *(const float4*)&Hs[wave][k][q * 4];  // uniform broadcast
        a0[k] += hq.x * wA.x + hq.y * wA.y + hq.z * wA.z + hq.w * wA.w;
        a1[k] += hq.x * wB.x + hq.y * wB.y + hq.z * wB.z + hq.w * wB.w;
      }
    }
#pragma unroll
    for (int k = 0; k < 4; k++) {
      if (sb + k < end) {
        float2 o = make_float2(a0[k] * INV_HID, a1[k] * INV_HID);
        ((float2*)wm)[(size_t)sl[k] * 64 + (hi ? 32 : 0) + v] = o;
      }
    }
  }
}

// ---------------- attention pass (wave-per-node, degree-sorted) ----------------
__global__ __launch_bounds__(256) void k_att(
    const int* __restrict__ rowptr,
    const int* __restrict__ nperm,     // degree-sorted node ids
    const int* __restrict__ srcc,      // E, CSR order
    const float* __restrict__ ec,      // E x 4, CSR order
    const float* __restrict__ cc,      // E, CSR order
    const float* __restrict__ node_f,  // N x 128
    const float* __restrict__ wm,      // E x 128 (K-MLP, INV_HID folded)
    const float* __restrict__ A,       // N x 1024 (lane-contiguous layout)
    float* __restrict__ sa_out,        // E x 4, CSR slot order
    int N)
{
  __shared__ float expws[4][MAXD][4];  // per-wave

  int t = threadIdx.x;
  int wave = t >> 6, lane = t & 63;
  int idx = blockIdx.x * 4 + wave;
  if (idx >= N) return;
  int n = nperm[idx];
  int row0 = rowptr[n];
  int deg = min(rowptr[n + 1] - row0, MAXD);
  if (deg <= 0) return;

  int v = lane & 31;
  bool hi = lane >= 32;
  int kk = (lane >> 2) & 3;

  // A fragments in registers
  float aS[4], aV[12];
  {
    const float* Ab = A + (size_t)n * 1024;
    const float* ps = Ab + (hi ? 128 : 0) + v * 4;
    float4 t0 = *(const float4*)ps;
    aS[0] = t0.x; aS[1] = t0.y; aS[2] = t0.z; aS[3] = t0.w;
    const float* pv = Ab + (hi ? 640 : 256) + v * 12;
    float4 u0 = *(const float4*)pv;
    float4 u1 = *(const float4*)(pv + 4);
    float4 u2 = *(const float4*)(pv + 8);
    aV[0] = u0.x; aV[1] = u0.y; aV[2]  = u0.z; aV[3]  = u0.w;
    aV[4] = u1.x; aV[5] = u1.y; aV[6]  = u1.z; aV[7]  = u1.w;
    aV[8] = u2.x; aV[9] = u2.y; aV[10] = u2.z; aV[11] = u2.w;
  }

  int iters = (deg + 3) >> 2;
  float zacc = 0.f;  // lanes 0..15: partial z for (kk, h2=lane&3)

  for (int it = 0; it < iters; ++it) {
    int sb = it * 4;
    int slot[4]; int sp[4];
#pragma unroll
    for (int k = 0; k < 4; k++) slot[k] = row0 + min(sb + k, deg - 1);
#pragma unroll
    for (int k = 0; k < 4; k++) sp[k] = srcc[slot[k]];
    float4 ya[4]; float cf[4]; float2 wj[4]; float s0[4], s1[4], s2[4];
#pragma unroll
    for (int k = 0; k < 4; k++) {
      ya[k] = ((const float4*)ec)[slot[k]];
      cf[k] = (sb + k < deg) ? cc[slot[k]] : 0.f;   // OOB -> expw 0
      wj[k] = ((const float2*)wm)[(size_t)slot[k] * 64 + (hi ? 32 : 0) + v];
      const float* nf = &node_f[(size_t)sp[k] * 128];
      if (!hi) { s0[k] = nf[v]; s1[k] = 0.f; s2[k] = 0.f; }
      else     { s0[k] = nf[32 + v * 3]; s1[k] = nf[33 + v * 3]; s2[k] = nf[34 + v * 3]; }
    }
    // attention logits; p[m], m = k*4 + h2
    float p[16];
#pragma unroll
    for (int k = 0; k < 4; k++) {
      float ys = ya[k].x, yv0 = ya[k].y, yv1 = ya[k].z, yv2 = ya[k].w;
      if (!hi) {  // lanes 0..31: k0 (row 0) + kv0 (row 2)
        float k0 = wj[k].x * s0[k] * ys;
        float kb = INV3 * wj[k].y * s0[k];
#pragma unroll
        for (int h2 = 0; h2 < 4; h2++)
          p[k * 4 + h2] = aS[h2] * k0 +
              kb * (aV[h2 * 3] * yv0 + aV[h2 * 3 + 1] * yv1 + aV[h2 * 3 + 2] * yv2);
      } else {    // lanes 32..63: k1 (row 1) + kv1 (row 3)
        float dotv = s0[k] * yv0 + s1[k] * yv1 + s2[k] * yv2;
        float k1 = wj[k].x * dotv * INV3;
        float kc = INV3 * wj[k].y * ys;
#pragma unroll
        for (int h2 = 0; h2 < 4; h2++)
          p[k * 4 + h2] = aS[h2] * k1 +
              kc * (aV[h2 * 3] * s0[k] + aV[h2 * 3 + 1] * s1[k] + aV[h2 * 3 + 2] * s2[k]);
      }
    }
    // folded butterfly: 16 per-lane values -> full sums keyed by lane&15
    bool fb0 = (lane & 1) != 0;
    float q8[8];
#pragma unroll
    for (int j = 0; j < 8; j++) {
      float a = p[2 * j], b = p[2 * j + 1];
      float keep = fb0 ? b : a, send = fb0 ? a : b;
      q8[j] = keep + __shfl_xor(send, 1, 64);
    }
    bool fb1 = (lane & 2) != 0;
    float r4[4];
#pragma unroll
    for (int j = 0; j < 4; j++) {
      float a = q8[2 * j], b = q8[2 * j + 1];
      float keep = fb1 ? b : a, send = fb1 ? a : b;
      r4[j] = keep + __shfl_xor(send, 2, 64);
    }
    bool fb2 = (lane & 4) != 0;
    float s2v[2];
#pragma unroll
    for (int j = 0; j < 2; j++) {
      float a = r4[2 * j], b = r4[2 * j + 1];
      float keep = fb2 ? b : a, send = fb2 ? a : b;
      s2v[j] = keep + __shfl_xor(send, 4, 64);
    }
    bool fb3 = (lane & 8) != 0;
    float w;
    {
      float a = s2v[0], b = s2v[1];
      float keep = fb3 ? b : a, send = fb3 ? a : b;
      w = keep + __shfl_xor(send, 8, 64);
    }
    w += __shfl_xor(w, 16, 64);
    w += __shfl_xor(w, 32, 64);
    // lane l holds sum for edge (l>>2)&3, head l&3
    float cA = (lane & 4) ? cf[1] : cf[0];
    float cB = (lane & 4) ? cf[3] : cf[2];
    float cfs = (lane & 8) ? cB : cA;
    int slotw = sb + kk;
    float ex = cfs * __expf(w * INV_FAN);
    if (lane < 16 && slotw < deg) {
      expws[wave][slotw][lane & 3] = ex;
      zacc += ex;
    }
  }
  // z reduce: lanes 0..15 hold partials (kk, h2=lane&3); sum over kk
  float zr = zacc;
  zr += __shfl_xor(zr, 4, 64);
  zr += __shfl_xor(zr, 8, 64);
  float zf = __shfl(zr, lane & 3, 64);
  zf = (zf == 0.f) ? 1.f : zf;
  for (int i = lane; i < deg * 4; i += 64) {
    int slot = i >> 2;  // i&3 == lane&3
    float alpha = expws[wave][slot][lane & 3] / zf;
    sa_out[(size_t)(row0 + slot) * 4 + (lane & 3)] = sqrtf(fmaxf(alpha, 0.f));
  }
}

// ---------------- aggregation pass + output linear ----------------
__global__ __launch_bounds__(256) void k_agg(
    const int* __restrict__ rowptr,
    const int* __restrict__ nperm,
    const int* __restrict__ srcc,
    const float* __restrict__ ec,
    const float* __restrict__ node_f,
    const float* __restrict__ wm,      // E x 128 (V-MLP, INV_HID folded)
    const float* __restrict__ Wls, const float* __restrict__ Wlv,  // 64x32 each
    const float* __restrict__ sa_in,   // E x 4, CSR slot order
    float* __restrict__ out,           // N x 128
    int N)
{
  __shared__ float aggv[4][256];  // [wave][ch']: ch'=u (s) | 64+d*64+u (v)

  int t = threadIdx.x;
  int wave = t >> 6, lane = t & 63;
  int idx = blockIdx.x * 4 + wave;
  if (idx >= N) return;
  int n = nperm[idx];
  int row0 = rowptr[n];
  int deg = min(rowptr[n + 1] - row0, MAXD);

  int v = lane & 31;
  bool hi = lane >= 32;
  int hh = v >> 3;  // head of channel v (m = MUL/H = 8)
  float accS = 0.f, acc0 = 0.f, acc1 = 0.f, acc2 = 0.f;

  if (deg > 0) {
    int iters = (deg + 3) >> 2;
    for (int it = 0; it < iters; ++it) {
      int sb = it * 4;
      int slot[4]; int sp[4];
#pragma unroll
      for (int k = 0; k < 4; k++) slot[k] = row0 + min(sb + k, deg - 1);
#pragma unroll
      for (int k = 0; k < 4; k++) sp[k] = srcc[slot[k]];
      float4 ya[4]; float sav[4]; float2 wj[4]; float s0[4], s1[4], s2[4];
#pragma unroll
      for (int k = 0; k < 4; k++) {
        sav[k] = (sb + k < deg) ? sa_in[(size_t)slot[k] * 4 + hh] : 0.f;  // OOB -> 0
        ya[k] = ((const float4*)ec)[slot[k]];
        wj[k] = ((const float2*)wm)[(size_t)slot[k] * 64 + (hi ? 32 : 0) + v];
        const float* nf = &node_f[(size_t)sp[k] * 128];
        if (!hi) { s0[k] = nf[v]; s1[k] = 0.f; s2[k] = 0.f; }
        else     { s0[k] = nf[32 + v * 3]; s1[k] = nf[33 + v * 3]; s2[k] = nf[34 + v * 3]; }
      }
#pragma unroll
      for (int k = 0; k < 4; k++) {
        float ys = ya[k].x, yv0 = ya[k].y, yv1 = ya[k].z, yv2 = ya[k].w;
        float sav_k = sav[k];
        if (!hi) {  // v0 -> s-ch v ; vv0 -> v-ch (u=v, d)
          accS += wj[k].x * s0[k] * ys * sav_k;
          float b = wj[k].y * s0[k] * sav_k;
          acc0 += b * yv0; acc1 += b * yv1; acc2 += b * yv2;
        } else {    // v1 -> s-ch 32+v ; vv1 -> v-ch (u=32+v, d)
          float dotv = s0[k] * yv0 + s1[k] * yv1 + s2[k] * yv2;
          accS += wj[k].x * dotv * INV3 * sav_k;
          float c = wj[k].y * ys * sav_k;
          acc0 += c * s0[k]; acc1 += c * s1[k]; acc2 += c * s2[k];
        }
      }
    }
  }
  // wave-private aggregation + fused output linear (weights from L2)
  {
    int us = hi ? 32 + v : v;
    aggv[wave][us]       = accS;
    aggv[wave][64 + us]  = acc0;
    aggv[wave][128 + us] = acc1;
    aggv[wave][192 + us] = acc2;
    const float* agg = aggv[wave];   // in-wave DS ordering: writes precede reads
#pragma unroll
    for (int rep = 0; rep < 2; ++rep) {
      int o = lane + rep * 64;
      float acc = 0.f;
      if (o < 32) {
#pragma unroll
        for (int u = 0; u < 64; u++) acc += agg[u] * Wls[u * 32 + o];
      } else {
        int i = o - 32, w2 = i / 3, d = i - 3 * w2;
        const float* av = &agg[64 + d * 64];
#pragma unroll
        for (int u = 0; u < 64; u++) acc += av[u] * Wlv[u * 32 + w2];
      }
      out[(size_t)n * 128 + o] = acc * INV_L;
    }
  }
}

// ---------------- host launcher ----------------
extern "C" void kernel_launch(void* const* d_in, const int* in_sizes, int n_in,
                              void* d_out, int out_size, void* d_ws, size_t ws_size,
                              hipStream_t stream) {
  const int*   esrc   = (const int*)d_in[0];
  const int*   edst   = (const int*)d_in[1];
  const float* xattr  = (const float*)d_in[2];
  const float* eattr  = (const float*)d_in[3];
  const float* cutoff = (const float*)d_in[4];
  const float* node_f = (const float*)d_in[5];
  const float* wk1    = (const float*)d_in[6];
  const float* bk1    = (const float*)d_in[7];
  const float* wk2    = (const float*)d_in[8];
  const float* wv1    = (const float*)d_in[9];
  const float* bv1    = (const float*)d_in[10];
  const float* wv2    = (const float*)d_in[11];
  const float* Wdot   = (const float*)d_in[12];
  const float* Wls    = (const float*)d_in[13];
  const float* Wlv    = (const float*)d_in[14];
  float* out = (float*)d_out;

  int E = in_sizes[0];
  int N = in_sizes[5] / 128;

  // workspace layout (~230 MB; wm reused for K-MLP then V-MLP):
  float* A    = (float*)d_ws;                 // N*1024 f32
  float* sa   = A + (size_t)N * 1024;         // E*4 f32
  float* xc   = sa + (size_t)E * 4;           // E*8 f32 (CSR-ordered xattr)
  float* ec   = xc + (size_t)E * 8;           // E*4 f32 (CSR-ordered eattr)
  float* cc   = ec + (size_t)E * 4;           // E f32   (CSR-ordered cutoff)
  int* srcc   = (int*)(cc + (size_t)E);       // E       (CSR-ordered esrc)
  int* counts = srcc + E;                     // N   (zeroed)
  int* cursor = counts + N;                   // N   (zeroed)
  int* dbin   = cursor + N;                   // 128 (zeroed)
  int* dcur   = dbin + 128;                   // 128 (zeroed)
  int* rowptr = dcur + 128;                   // N+1
  int* doff   = rowptr + (N + 1);             // 128
  int* nperm  = doff + 128;                   // N
  int* csr    = nperm + N;                    // E
  float* wm   = (float*)(csr + E);            // E*128 f32 (163.8 MB)

  k_zero<<<(2 * N + 256 + 255) / 256, 256, 0, stream>>>(counts, 2 * N + 256);
  k_hist<<<(E + 255) / 256, 256, 0, stream>>>(edst, counts, E);
  k_scan<<<1, 256, 0, stream>>>(counts, rowptr, N);
  k_fill<<<(E + 255) / 256, 256, 0, stream>>>(edst, rowptr, cursor, csr, E);
  k_dhist<<<(N + 255) / 256, 256, 0, stream>>>(rowptr, dbin, N);
  k_dscan<<<1, 64, 0, stream>>>(dbin, doff);
  k_dfill<<<(N + 255) / 256, 256, 0, stream>>>(rowptr, doff, dcur, nperm, N);
  k_gather<<<(E + 255) / 256, 256, 0, stream>>>(csr, esrc, xattr, eattr, cutoff,
                                                xc, ec, cc, srcc, E);
  k_nodeA<<<(N + 31) / 32, 256, 0, stream>>>(node_f, Wdot, A, N);

  int mgrid = 768;                              // 3 blocks/CU = VGPR residency fill
  int chunk = (E + mgrid - 1) / mgrid;          // equal work per block
  int nb = (N + 3) / 4;                         // one node per wave

  k_mlp<<<mgrid, 256, 0, stream>>>(xc, wk1, bk1, wk2, wm, E, chunk);
  k_att<<<nb, 256, 0, stream>>>(rowptr, nperm, srcc, ec, cc, node_f, wm, A, sa, N);
  k_mlp<<<mgrid, 256, 0, stream>>>(xc, wv1, bv1, wv2, wm, E, chunk);
  k_agg<<<nb, 256, 0, stream>>>(rowptr, nperm, srcc, ec, node_f, wm,
                                Wls, Wlv, sa, out, N);
}

// Round 16
// 866.622 us; speedup vs baseline: 1.5355x; 1.0175x over previous
//
#include <hip/hip_runtime.h>

// Equivariant graph attention (Transformer_41480794145180) — fp32 throughout.
//
// Pipeline (all on `stream`):
//   k_zero/k_hist/k_scan/k_fill : build CSR of edges grouped by dst node
//   k_dhist/k_dscan/k_dfill     : counting-sort nodes by degree (descending)
//   k_gather: permute xattr/eattr/cutoff/esrc into CSR slot order
//   k_nodeA : per-node A fragments (lane-contiguous layout)
//   k_mlp(K): edge-parallel dense MLP -> wmK
//   k_mva   : FUSED single launch: blocks [0,mgrid) = V-MLP -> wmV;
//             blocks [mgrid,..) = attention pass reading wmK. The two are
//             independent; co-residency lets latency-bound att waves fill
//             the LDS-bound MLP waves' issue gaps. (Requires ws for wmK+wmV;
//             host checks ws_size and falls back to R15 serial order.)
//   k_agg   : wave-per-node: v-terms from wmV * sa -> wave agg -> out
//
// R16 (R15 post-mortem: grid 512->768 was NULL — occupancy pinned at 11%,
// k_mlp is per-CU LDS-pipe-bound, more waves just queue. 252us is this
// structure's floor. Remaining pipeline slack: k_mlp(V) and k_att are
// independent but serialized, each at ~11% occupancy):
//  - co-schedule k_mlp(V)+k_att in one launch (block-uniform branch).
//  - runtime ws_size check; graceful fallback to exact R15 behavior.

constexpr float INV3    = 0.57735026918962576f;  // 1/sqrt(3)
constexpr float INV_SQ8 = 0.35355339059327373f;  // 1/sqrt(N_BASIS=8)
constexpr float INV_HID = 0.125f;                // 1/sqrt(HID=64)
constexpr float INV_FAN = 0.015625f;             // 1/sqrt(4*32*32)
constexpr float INV_L   = 0.125f;                // 1/sqrt(2*MUL=64)
constexpr int   MAXD    = 128;                   // max in-degree (Poisson(32))

// jax.nn.gelu default (approximate=True, tanh form)
__device__ __forceinline__ float gelu_tanh(float x) {
  float u = 0.7978845608028654f * (x + 0.044715f * x * x * x);
  float e = __expf(2.0f * u);            // e=inf / e=0 limits are exact
  return x * (1.0f - 1.0f / (e + 1.0f)); // = 0.5x(1+tanh(u))
}

// ---------------- CSR build ----------------
__global__ void k_zero(int* __restrict__ p, int n) {
  int i = blockIdx.x * 256 + threadIdx.x;
  if (i < n) p[i] = 0;
}

__global__ void k_hist(const int* __restrict__ dst, int* __restrict__ cnt, int E) {
  int e = blockIdx.x * 256 + threadIdx.x;
  if (e < E) atomicAdd(&cnt[dst[e]], 1);
}

// single-block exclusive scan over N counts -> rowptr[0..N]
__global__ __launch_bounds__(256) void k_scan(const int* __restrict__ cnt,
                                              int* __restrict__ rowptr, int N) {
  __shared__ int wsum[4];
  __shared__ int woff[4];
  __shared__ int carry;
  int t = threadIdx.x, wave = t >> 6, lane = t & 63;
  if (t == 0) { carry = 0; rowptr[0] = 0; }
  __syncthreads();
  for (int base = 0; base < N; base += 256) {
    int i = base + t;
    int inc = (i < N) ? cnt[i] : 0;
#pragma unroll
    for (int off = 1; off < 64; off <<= 1) {
      int y = __shfl_up(inc, off, 64);
      if (lane >= off) inc += y;
    }
    if (lane == 63) wsum[wave] = inc;
    __syncthreads();
    if (t == 0) {
      int r = 0;
      for (int w = 0; w < 4; w++) { woff[w] = r; r += wsum[w]; }
    }
    __syncthreads();
    int incl = inc + woff[wave] + carry;
    if (i < N) rowptr[i + 1] = incl;
    __syncthreads();
    if (t == 255) carry = incl;  // padded lanes add 0, so this is the chunk total
    __syncthreads();
  }
}

__global__ void k_fill(const int* __restrict__ dst, const int* __restrict__ rowptr,
                       int* __restrict__ cursor, int* __restrict__ csr, int E) {
  int e = blockIdx.x * 256 + threadIdx.x;
  if (e < E) {
    int d = dst[e];
    int s = atomicAdd(&cursor[d], 1);
    csr[rowptr[d] + s] = e;
  }
}

// ---------------- degree counting sort (descending) ----------------
__global__ void k_dhist(const int* __restrict__ rowptr, int* __restrict__ dbin, int N) {
  int n = blockIdx.x * 256 + threadIdx.x;
  if (n < N) {
    int deg = rowptr[n + 1] - rowptr[n];
    atomicAdd(&dbin[min(deg, 127)], 1);
  }
}

__global__ void k_dscan(const int* __restrict__ dbin, int* __restrict__ doff) {
  if (threadIdx.x == 0 && blockIdx.x == 0) {
    int r = 0;
    for (int d = 127; d >= 0; --d) { doff[d] = r; r += dbin[d]; }
  }
}

__global__ void k_dfill(const int* __restrict__ rowptr, const int* __restrict__ doff,
                        int* __restrict__ dcur, int* __restrict__ nperm, int N) {
  int n = blockIdx.x * 256 + threadIdx.x;
  if (n < N) {
    int d = min(rowptr[n + 1] - rowptr[n], 127);
    int p = doff[d] + atomicAdd(&dcur[d], 1);
    nperm[p] = n;
  }
}

// permute edge arrays into CSR slot order (coalesced writes, random reads)
__global__ __launch_bounds__(256) void k_gather(
    const int* __restrict__ csr, const int* __restrict__ esrc,
    const float* __restrict__ xattr, const float* __restrict__ eattr,
    const float* __restrict__ cutoff,
    float* __restrict__ xc, float* __restrict__ ec, float* __restrict__ cc,
    int* __restrict__ srcc, int E) {
  int p = blockIdx.x * 256 + threadIdx.x;
  if (p >= E) return;
  int e = csr[p];
  srcc[p] = esrc[e];
  cc[p] = cutoff[e];
  ((float4*)ec)[p] = ((const float4*)eattr)[e];
  const float4* xs = (const float4*)xattr + (size_t)e * 2;
  float4* xd = (float4*)xc + (size_t)p * 2;
  xd[0] = xs[0]; xd[1] = xs[1];
}

// ---------------- per-node A precompute ----------------
// A layout per node (1024 f32), lane-contiguous:
//   A0[32][4] (v,h) | A1[32][4] | A2[32][4][3] (v,h,d) | A3[32][4][3]
__global__ __launch_bounds__(256) void k_nodeA(const float* __restrict__ node_f,
                                               const float* __restrict__ Wdot,
                                               float* __restrict__ A, int N) {
  __shared__ float Wd[16384];     // 64 KiB: W_dot[4][4][32][32]
  __shared__ float nfs[32 * 128]; // 16 KiB: 32 nodes' features
  int t = threadIdx.x;
  for (int i = t; i < 16384; i += 256) Wd[i] = Wdot[i];
  int n0 = blockIdx.x * 32;
  int nEnd = min(32, N - n0);
  for (int i = t; i < nEnd * 128; i += 256) nfs[i] = node_f[n0 * 128 + i];
  __syncthreads();
  for (int nn = 0; nn < nEnd; ++nn) {
    const float* nf = &nfs[nn * 128];
    float* An = &A[(n0 + nn) * 1024];
#pragma unroll
    for (int k = 0; k < 4; k++) {
      int o = t + k * 256;  // branch below is uniform per k (no divergence)
      float acc = 0.f;
      int idx;
      if (o < 256) {        // A0 / A1 : scalar q
        int term = o >> 7, h = (o >> 5) & 3, v = o & 31;
        const float* W = &Wd[term * 4096 + h * 1024 + v];
#pragma unroll
        for (int u = 0; u < 32; u++) acc += W[u * 32] * nf[u];
        idx = term * 128 + v * 4 + h;
      } else {              // A2 / A3 : vector q
        int r = o - 256;
        int term = r / 384;                 // 0,1 -> A2,A3
        int rr = r % 384;
        int h = rr / 96, q = rr % 96, v = q / 3, d = q - 3 * (q / 3);
        const float* W = &Wd[(term + 2) * 4096 + h * 1024 + v];
#pragma unroll
        for (int u = 0; u < 32; u++) acc += W[u * 32] * nf[32 + u * 3 + d];
        idx = 256 + term * 384 + v * 12 + h * 3 + d;
      }
      An[idx] = acc;
    }
  }
}

// ---------------- MLP body (device inline) ----------------
// wm[slot][128] layout: [lo half: (row0[v],row2[v]) pairs, v=0..31]
//                       [hi half: (row1[v],row3[v]) pairs, v=0..31]
// Pre-scaled by INV_HID. Input xc read LINEARLY by slot (CSR order).
// wq column index XOR-swizzled (j -> j^((j>>3)&7)) -> conflict-free reads.
__device__ __forceinline__ void mlp_body(
    const float* __restrict__ xc,
    const float* __restrict__ w1, const float* __restrict__ b1,
    const float* __restrict__ w2,
    float* __restrict__ wm, int E, int chunk, int blk,
    float* w1s, float* b1s, float (*wq)[128][4], float (*Hs)[4][64]) {
  int t = threadIdx.x;
  int wave = t >> 6, lane = t & 63;
  for (int i = t; i < 512; i += 256) w1s[i] = w1[i];
  if (t < 64) b1s[t] = b1[t];
  for (int i = t; i < 8192; i += 256) {
    int l = i >> 7, j = i & 127;
    int js = j ^ ((j >> 3) & 7);                  // swizzled column
    wq[l >> 2][js][l & 3] = w2[i];
  }
  __syncthreads();

  int base = blk * chunk;
  int end = min(base + chunk, E);
  int v = lane & 31;
  bool hi = lane >= 32;
  int c0 = lane, c1 = lane + 64;
  int c0s = c0 ^ ((c0 >> 3) & 7);
  int c1s = c1 ^ ((c1 >> 3) & 7);

  for (int sb = base + wave * 4; sb < end; sb += 16) {
    int sl[4];
#pragma unroll
    for (int k = 0; k < 4; k++) sl[k] = min(sb + k, E - 1);
    float h[4];
#pragma unroll
    for (int k = 0; k < 4; k++) {
      const float4* xp = (const float4*)xc + (size_t)sl[k] * 2;  // linear stream
      float4 xa = xp[0], xb = xp[1];
      float acc = xa.x * w1s[lane]       + xa.y * w1s[64 + lane]
                + xa.z * w1s[128 + lane] + xa.w * w1s[192 + lane]
                + xb.x * w1s[256 + lane] + xb.y * w1s[320 + lane]
                + xb.z * w1s[384 + lane] + xb.w * w1s[448 + lane];
      h[k] = gelu_tanh(acc * INV_SQ8 + b1s[lane]);
    }
#pragma unroll
    for (int k = 0; k < 4; k++) Hs[wave][k][lane] = h[k];  // wave-private
    float a0[4] = {0, 0, 0, 0}, a1[4] = {0, 0, 0, 0};
#pragma unroll
    for (int q = 0; q < 16; q++) {
      float4 wA = *(const float4*)&wq[q][c0s][0];   // conflict-free (swizzled)
      float4 wB = *(const float4*)&wq[q][c1s][0];
#pragma unroll
      for (int k = 0; k < 4; k++) {
        float4 hq = *(const float4*)&Hs[wave][k][q * 4];  // uniform broadcast
        a0[k] += hq.x * wA.x + hq.y * wA.y + hq.z * wA.z + hq.w * wA.w;
        a1[k] += hq.x * wB.x + hq.y * wB.y + hq.z * wB.z + hq.w * wB.w;
      }
    }
#pragma unroll
    for (int k = 0; k < 4; k++) {
      if (sb + k < end) {
        float2 o = make_float2(a0[k] * INV_HID, a1[k] * INV_HID);
        ((float2*)wm)[(size_t)sl[k] * 64 + (hi ? 32 : 0) + v] = o;
      }
    }
  }
}

// ---------------- attention body (device inline) ----------------
__device__ __forceinline__ void att_body(
    const int* __restrict__ rowptr, const int* __restrict__ nperm,
    const int* __restrict__ srcc, const float* __restrict__ ec,
    const float* __restrict__ cc, const float* __restrict__ node_f,
    const float* __restrict__ wm, const float* __restrict__ A,
    float* __restrict__ sa_out, int N, int blk,
    float (*expws)[MAXD][4]) {
  int t = threadIdx.x;
  int wave = t >> 6, lane = t & 63;
  int idx = blk * 4 + wave;
  if (idx >= N) return;
  int n = nperm[idx];
  int row0 = rowptr[n];
  int deg = min(rowptr[n + 1] - row0, MAXD);
  if (deg <= 0) return;

  int v = lane & 31;
  bool hi = lane >= 32;
  int kk = (lane >> 2) & 3;

  float aS[4], aV[12];
  {
    const float* Ab = A + (size_t)n * 1024;
    const float* ps = Ab + (hi ? 128 : 0) + v * 4;
    float4 t0 = *(const float4*)ps;
    aS[0] = t0.x; aS[1] = t0.y; aS[2] = t0.z; aS[3] = t0.w;
    const float* pv = Ab + (hi ? 640 : 256) + v * 12;
    float4 u0 = *(const float4*)pv;
    float4 u1 = *(const float4*)(pv + 4);
    float4 u2 = *(const float4*)(pv + 8);
    aV[0] = u0.x; aV[1] = u0.y; aV[2]  = u0.z; aV[3]  = u0.w;
    aV[4] = u1.x; aV[5] = u1.y; aV[6]  = u1.z; aV[7]  = u1.w;
    aV[8] = u2.x; aV[9] = u2.y; aV[10] = u2.z; aV[11] = u2.w;
  }

  int iters = (deg + 3) >> 2;
  float zacc = 0.f;  // lanes 0..15: partial z for (kk, h2=lane&3)

  for (int it = 0; it < iters; ++it) {
    int sb = it * 4;
    int slot[4]; int sp[4];
#pragma unroll
    for (int k = 0; k < 4; k++) slot[k] = row0 + min(sb + k, deg - 1);
#pragma unroll
    for (int k = 0; k < 4; k++) sp[k] = srcc[slot[k]];
    float4 ya[4]; float cf[4]; float2 wj[4]; float s0[4], s1[4], s2[4];
#pragma unroll
    for (int k = 0; k < 4; k++) {
      ya[k] = ((const float4*)ec)[slot[k]];
      cf[k] = (sb + k < deg) ? cc[slot[k]] : 0.f;   // OOB -> expw 0
      wj[k] = ((const float2*)wm)[(size_t)slot[k] * 64 + (hi ? 32 : 0) + v];
      const float* nf = &node_f[(size_t)sp[k] * 128];
      if (!hi) { s0[k] = nf[v]; s1[k] = 0.f; s2[k] = 0.f; }
      else     { s0[k] = nf[32 + v * 3]; s1[k] = nf[33 + v * 3]; s2[k] = nf[34 + v * 3]; }
    }
    float p[16];
#pragma unroll
    for (int k = 0; k < 4; k++) {
      float ys = ya[k].x, yv0 = ya[k].y, yv1 = ya[k].z, yv2 = ya[k].w;
      if (!hi) {
        float k0 = wj[k].x * s0[k] * ys;
        float kb = INV3 * wj[k].y * s0[k];
#pragma unroll
        for (int h2 = 0; h2 < 4; h2++)
          p[k * 4 + h2] = aS[h2] * k0 +
              kb * (aV[h2 * 3] * yv0 + aV[h2 * 3 + 1] * yv1 + aV[h2 * 3 + 2] * yv2);
      } else {
        float dotv = s0[k] * yv0 + s1[k] * yv1 + s2[k] * yv2;
        float k1 = wj[k].x * dotv * INV3;
        float kc = INV3 * wj[k].y * ys;
#pragma unroll
        for (int h2 = 0; h2 < 4; h2++)
          p[k * 4 + h2] = aS[h2] * k1 +
              kc * (aV[h2 * 3] * s0[k] + aV[h2 * 3 + 1] * s1[k] + aV[h2 * 3 + 2] * s2[k]);
      }
    }
    // folded butterfly: 16 per-lane values -> full sums keyed by lane&15
    bool fb0 = (lane & 1) != 0;
    float q8[8];
#pragma unroll
    for (int j = 0; j < 8; j++) {
      float a = p[2 * j], b = p[2 * j + 1];
      float keep = fb0 ? b : a, send = fb0 ? a : b;
      q8[j] = keep + __shfl_xor(send, 1, 64);
    }
    bool fb1 = (lane & 2) != 0;
    float r4[4];
#pragma unroll
    for (int j = 0; j < 4; j++) {
      float a = q8[2 * j], b = q8[2 * j + 1];
      float keep = fb1 ? b : a, send = fb1 ? a : b;
      r4[j] = keep + __shfl_xor(send, 2, 64);
    }
    bool fb2 = (lane & 4) != 0;
    float s2v[2];
#pragma unroll
    for (int j = 0; j < 2; j++) {
      float a = r4[2 * j], b = r4[2 * j + 1];
      float keep = fb2 ? b : a, send = fb2 ? a : b;
      s2v[j] = keep + __shfl_xor(send, 4, 64);
    }
    bool fb3 = (lane & 8) != 0;
    float w;
    {
      float a = s2v[0], b = s2v[1];
      float keep = fb3 ? b : a, send = fb3 ? a : b;
      w = keep + __shfl_xor(send, 8, 64);
    }
    w += __shfl_xor(w, 16, 64);
    w += __shfl_xor(w, 32, 64);
    float cA = (lane & 4) ? cf[1] : cf[0];
    float cB = (lane & 4) ? cf[3] : cf[2];
    float cfs = (lane & 8) ? cB : cA;
    int slotw = sb + kk;
    float ex = cfs * __expf(w * INV_FAN);
    if (lane < 16 && slotw < deg) {
      expws[wave][slotw][lane & 3] = ex;
      zacc += ex;
    }
  }
  float zr = zacc;
  zr += __shfl_xor(zr, 4, 64);
  zr += __shfl_xor(zr, 8, 64);
  float zf = __shfl(zr, lane & 3, 64);
  zf = (zf == 0.f) ? 1.f : zf;
  for (int i = lane; i < deg * 4; i += 64) {
    int slot = i >> 2;  // i&3 == lane&3
    float alpha = expws[wave][slot][lane & 3] / zf;
    sa_out[(size_t)(row0 + slot) * 4 + (lane & 3)] = sqrtf(fmaxf(alpha, 0.f));
  }
}

// ---------------- standalone kernels ----------------
__global__ __launch_bounds__(256) void k_mlp(
    const float* __restrict__ xc,
    const float* __restrict__ w1, const float* __restrict__ b1,
    const float* __restrict__ w2,
    float* __restrict__ wm, int E, int chunk) {
  __shared__ __align__(16) float w1s[512];
  __shared__ float b1s[64];
  __shared__ __align__(16) float wq[16][128][4];
  __shared__ __align__(16) float Hs[4][4][64];
  mlp_body(xc, w1, b1, w2, wm, E, chunk, blockIdx.x, w1s, b1s, wq, Hs);
}

__global__ __launch_bounds__(256) void k_att(
    const int* __restrict__ rowptr, const int* __restrict__ nperm,
    const int* __restrict__ srcc, const float* __restrict__ ec,
    const float* __restrict__ cc, const float* __restrict__ node_f,
    const float* __restrict__ wm, const float* __restrict__ A,
    float* __restrict__ sa_out, int N) {
  __shared__ float expws[4][MAXD][4];
  att_body(rowptr, nperm, srcc, ec, cc, node_f, wm, A, sa_out, N,
           blockIdx.x, expws);
}

// fused: blocks [0,mgrid) run V-MLP; blocks [mgrid,..) run attention
__global__ __launch_bounds__(256) void k_mva(
    const float* __restrict__ xc,
    const float* __restrict__ wv1, const float* __restrict__ bv1,
    const float* __restrict__ wv2,
    float* __restrict__ wmV, int E, int chunk, int mgrid,
    const int* __restrict__ rowptr, const int* __restrict__ nperm,
    const int* __restrict__ srcc, const float* __restrict__ ec,
    const float* __restrict__ cc, const float* __restrict__ node_f,
    const float* __restrict__ wmK, const float* __restrict__ A,
    float* __restrict__ sa_out, int N) {
  // LDS union (both allocated; 39.4K + 8K = 47.4K -> still >=2 blocks/CU)
  __shared__ __align__(16) float w1s[512];
  __shared__ float b1s[64];
  __shared__ __align__(16) float wq[16][128][4];
  __shared__ __align__(16) float Hs[4][4][64];
  __shared__ float expws[4][MAXD][4];
  if ((int)blockIdx.x < mgrid) {
    mlp_body(xc, wv1, bv1, wv2, wmV, E, chunk, blockIdx.x, w1s, b1s, wq, Hs);
  } else {
    att_body(rowptr, nperm, srcc, ec, cc, node_f, wmK, A, sa_out, N,
             blockIdx.x - mgrid, expws);
  }
}

// ---------------- aggregation pass + output linear ----------------
__global__ __launch_bounds__(256) void k_agg(
    const int* __restrict__ rowptr,
    const int* __restrict__ nperm,
    const int* __restrict__ srcc,
    const float* __restrict__ ec,
    const float* __restrict__ node_f,
    const float* __restrict__ wm,      // E x 128 (V-MLP, INV_HID folded)
    const float* __restrict__ Wls, const float* __restrict__ Wlv,  // 64x32 each
    const float* __restrict__ sa_in,   // E x 4, CSR slot order
    float* __restrict__ out,           // N x 128
    int N)
{
  __shared__ float aggv[4][256];  // [wave][ch']: ch'=u (s) | 64+d*64+u (v)

  int t = threadIdx.x;
  int wave = t >> 6, lane = t & 63;
  int idx = blockIdx.x * 4 + wave;
  if (idx >= N) return;
  int n = nperm[idx];
  int row0 = rowptr[n];
  int deg = min(rowptr[n + 1] - row0, MAXD);

  int v = lane & 31;
  bool hi = lane >= 32;
  int hh = v >> 3;  // head of channel v (m = MUL/H = 8)
  float accS = 0.f, acc0 = 0.f, acc1 = 0.f, acc2 = 0.f;

  if (deg > 0) {
    int iters = (deg + 3) >> 2;
    for (int it = 0; it < iters; ++it) {
      int sb = it * 4;
      int slot[4]; int sp[4];
#pragma unroll
      for (int k = 0; k < 4; k++) slot[k] = row0 + min(sb + k, deg - 1);
#pragma unroll
      for (int k = 0; k < 4; k++) sp[k] = srcc[slot[k]];
      float4 ya[4]; float sav[4]; float2 wj[4]; float s0[4], s1[4], s2[4];
#pragma unroll
      for (int k = 0; k < 4; k++) {
        sav[k] = (sb + k < deg) ? sa_in[(size_t)slot[k] * 4 + hh] : 0.f;  // OOB -> 0
        ya[k] = ((const float4*)ec)[slot[k]];
        wj[k] = ((const float2*)wm)[(size_t)slot[k] * 64 + (hi ? 32 : 0) + v];
        const float* nf = &node_f[(size_t)sp[k] * 128];
        if (!hi) { s0[k] = nf[v]; s1[k] = 0.f; s2[k] = 0.f; }
        else     { s0[k] = nf[32 + v * 3]; s1[k] = nf[33 + v * 3]; s2[k] = nf[34 + v * 3]; }
      }
#pragma unroll
      for (int k = 0; k < 4; k++) {
        float ys = ya[k].x, yv0 = ya[k].y, yv1 = ya[k].z, yv2 = ya[k].w;
        float sav_k = sav[k];
        if (!hi) {  // v0 -> s-ch v ; vv0 -> v-ch (u=v, d)
          accS += wj[k].x * s0[k] * ys * sav_k;
          float b = wj[k].y * s0[k] * sav_k;
          acc0 += b * yv0; acc1 += b * yv1; acc2 += b * yv2;
        } else {    // v1 -> s-ch 32+v ; vv1 -> v-ch (u=32+v, d)
          float dotv = s0[k] * yv0 + s1[k] * yv1 + s2[k] * yv2;
          accS += wj[k].x * dotv * INV3 * sav_k;
          float c = wj[k].y * ys * sav_k;
          acc0 += c * s0[k]; acc1 += c * s1[k]; acc2 += c * s2[k];
        }
      }
    }
  }
  // wave-private aggregation + fused output linear (weights from L2)
  {
    int us = hi ? 32 + v : v;
    aggv[wave][us]       = accS;
    aggv[wave][64 + us]  = acc0;
    aggv[wave][128 + us] = acc1;
    aggv[wave][192 + us] = acc2;
    const float* agg = aggv[wave];   // in-wave DS ordering: writes precede reads
#pragma unroll
    for (int rep = 0; rep < 2; ++rep) {
      int o = lane + rep * 64;
      float acc = 0.f;
      if (o < 32) {
#pragma unroll
        for (int u = 0; u < 64; u++) acc += agg[u] * Wls[u * 32 + o];
      } else {
        int i = o - 32, w2 = i / 3, d = i - 3 * w2;
        const float* av = &agg[64 + d * 64];
#pragma unroll
        for (int u = 0; u < 64; u++) acc += av[u] * Wlv[u * 32 + w2];
      }
      out[(size_t)n * 128 + o] = acc * INV_L;
    }
  }
}

// ---------------- host launcher ----------------
extern "C" void kernel_launch(void* const* d_in, const int* in_sizes, int n_in,
                              void* d_out, int out_size, void* d_ws, size_t ws_size,
                              hipStream_t stream) {
  const int*   esrc   = (const int*)d_in[0];
  const int*   edst   = (const int*)d_in[1];
  const float* xattr  = (const float*)d_in[2];
  const float* eattr  = (const float*)d_in[3];
  const float* cutoff = (const float*)d_in[4];
  const float* node_f = (const float*)d_in[5];
  const float* wk1    = (const float*)d_in[6];
  const float* bk1    = (const float*)d_in[7];
  const float* wk2    = (const float*)d_in[8];
  const float* wv1    = (const float*)d_in[9];
  const float* bv1    = (const float*)d_in[10];
  const float* wv2    = (const float*)d_in[11];
  const float* Wdot   = (const float*)d_in[12];
  const float* Wls    = (const float*)d_in[13];
  const float* Wlv    = (const float*)d_in[14];
  float* out = (float*)d_out;

  int E = in_sizes[0];
  int N = in_sizes[5] / 128;

  // workspace layout (~230 MB base; +164 MB wmV when ws permits):
  float* A    = (float*)d_ws;                 // N*1024 f32
  float* sa   = A + (size_t)N * 1024;         // E*4 f32
  float* xc   = sa + (size_t)E * 4;           // E*8 f32 (CSR-ordered xattr)
  float* ec   = xc + (size_t)E * 8;           // E*4 f32 (CSR-ordered eattr)
  float* cc   = ec + (size_t)E * 4;           // E f32   (CSR-ordered cutoff)
  int* srcc   = (int*)(cc + (size_t)E);       // E       (CSR-ordered esrc)
  int* counts = srcc + E;                     // N   (zeroed)
  int* cursor = counts + N;                   // N   (zeroed)
  int* dbin   = cursor + N;                   // 128 (zeroed)
  int* dcur   = dbin + 128;                   // 128 (zeroed)
  int* rowptr = dcur + 128;                   // N+1
  int* doff   = rowptr + (N + 1);             // 128
  int* nperm  = doff + 128;                   // N
  int* csr    = nperm + N;                    // E
  float* wmK  = (float*)(csr + E);            // E*128 f32 (163.8 MB)
  float* wmV  = wmK + (size_t)E * 128;        // E*128 f32 (if ws permits)

  size_t need_fused = (size_t)((char*)(wmV + (size_t)E * 128) - (char*)d_ws);
  bool fused = ws_size >= need_fused;
  if (!fused) wmV = wmK;  // serial fallback reuses the single buffer

  k_zero<<<(2 * N + 256 + 255) / 256, 256, 0, stream>>>(counts, 2 * N + 256);
  k_hist<<<(E + 255) / 256, 256, 0, stream>>>(edst, counts, E);
  k_scan<<<1, 256, 0, stream>>>(counts, rowptr, N);
  k_fill<<<(E + 255) / 256, 256, 0, stream>>>(edst, rowptr, cursor, csr, E);
  k_dhist<<<(N + 255) / 256, 256, 0, stream>>>(rowptr, dbin, N);
  k_dscan<<<1, 64, 0, stream>>>(dbin, doff);
  k_dfill<<<(N + 255) / 256, 256, 0, stream>>>(rowptr, doff, dcur, nperm, N);
  k_gather<<<(E + 255) / 256, 256, 0, stream>>>(csr, esrc, xattr, eattr, cutoff,
                                                xc, ec, cc, srcc, E);
  k_nodeA<<<(N + 31) / 32, 256, 0, stream>>>(node_f, Wdot, A, N);

  int mgrid = 512;
  int chunk = (E + mgrid - 1) / mgrid;
  int nb = (N + 3) / 4;  // one node per wave

  k_mlp<<<mgrid, 256, 0, stream>>>(xc, wk1, bk1, wk2, wmK, E, chunk);
  if (fused) {
    // co-scheduled: V-MLP (blocks [0,mgrid)) + attention (blocks [mgrid,..))
    k_mva<<<mgrid + nb, 256, 0, stream>>>(xc, wv1, bv1, wv2, wmV, E, chunk,
                                          mgrid, rowptr, nperm, srcc, ec, cc,
                                          node_f, wmK, A, sa, N);
  } else {
    k_att<<<nb, 256, 0, stream>>>(rowptr, nperm, srcc, ec, cc, node_f,
                                  wmK, A, sa, N);
    k_mlp<<<mgrid, 256, 0, stream>>>(xc, wv1, bv1, wv2, wmV, E, chunk);
  }
  k_agg<<<nb, 256, 0, stream>>>(rowptr, nperm, srcc, ec, node_f, wmV,
                                Wls, Wlv, sa, out, N);
}